// Round 1
// baseline (57905.353 us; speedup 1.0000x reference)
//
#include <hip/hip_runtime.h>
#include <hip/hip_bf16.h>

// LinearCDE: y_{t+1} = y_t + A_t y_t + b_t, A_t = reshape(vf_A_W @ u_t, HxH),
// u_t = [1, X[:,t+1]] * DT.  CLIP=1e11 => CLIP*tanh(st/CLIP) == st to ~1e-10
// relative (|st| <= ~3e8), so tanh is skipped.
//
// B=8 S=512 D=64 H=128.
#define DT 0.025f
#define Bz 8
#define Sz 512
#define Dz 64
#define Hz 128
#define NT 511            // S-1 time steps in the scan
#define BT (Bz * NT)      // 4088 (b,t) pairs
#define OO (Hz * Hz)      // 16384 rows of vf_A_W
#define KK (Dz + 1)       // 65

// ---------------- ws layout (fast path) ----------------
// Wt  : [65][16384] f32            = 4,259,840 B
// Bs  : [4088][128] f32            = 2,093,056 B
// As  : [4088][16384] f32          = 267,911,168 B
#define WT_OFF  0ull
#define BS_OFF  4259840ull
#define AS_OFF  6352896ull
#define WS_NEED 274264064ull

// -------- transpose vf_A_W (o,d) -> Wt (d,o), coalesced writes --------
__global__ __launch_bounds__(256) void k_wt(const float* __restrict__ WA,
                                            float* __restrict__ Wt) {
    int o = blockIdx.x * 256 + threadIdx.x;           // 64 blocks
    const float* row = WA + (size_t)o * KK;
    for (int d = 0; d < KK; ++d)
        Wt[(size_t)d * OO + o] = row[d];
}

// -------- y0 = X[:,0] @ init_W^T + init_b, write to out[:,0,:] --------
__global__ __launch_bounds__(256) void k_y0(const float* __restrict__ X,
                                            const float* __restrict__ W,
                                            const float* __restrict__ bias,
                                            float* __restrict__ out) {
    int idx = blockIdx.x * 256 + threadIdx.x;         // 4 blocks, 1024 total
    int b = idx >> 7, h = idx & 127;
    const float* xr = X + (size_t)b * Sz * Dz;        // X[b,0,:]
    const float* wr = W + (size_t)h * Dz;
    float acc = bias[h];
    for (int d = 0; d < Dz; ++d) acc += xr[d] * wr[d];
    out[(size_t)b * Sz * Hz + h] = acc;
}

// -------- Bs[bt,h] = DT * (WB[h,0] + sum_k X[b,t+1,k] * WB[h,1+k]) --------
__global__ __launch_bounds__(256) void k_bs(const float* __restrict__ X,
                                            const float* __restrict__ WB,
                                            float* __restrict__ Bs) {
    int idx = blockIdx.x * 256 + threadIdx.x;         // 2044 blocks
    int bt = idx >> 7, h = idx & 127;
    int b = bt / NT, t = bt - b * NT;
    const float* xr = X + ((size_t)b * Sz + t + 1) * Dz;
    const float* wr = WB + (size_t)h * KK;
    float acc = wr[0];
    for (int k = 0; k < Dz; ++k) acc += xr[k] * wr[1 + k];
    Bs[(size_t)bt * Hz + h] = acc * DT;
}

// -------- As GEMM: As[bt, o] = sum_d u[bt,d] * Wt[d, o] --------
// tile: 16 bt x 1024 o per block; thread: 4 consecutive o x 16 bt accumulators
__global__ __launch_bounds__(256) void k_gemm(const float* __restrict__ X,
                                              const float* __restrict__ Wt,
                                              float* __restrict__ As) {
    __shared__ __align__(16) float u_lds[KK][16];
    const int tid = threadIdx.x;
    const int obase = blockIdx.x * 1024;              // 16 o-tiles
    const int btbase = blockIdx.y * 16;               // 256 bt-tiles

    for (int idx = tid; idx < KK * 16; idx += 256) {
        int d = idx >> 4, bt = idx & 15;
        int btg = btbase + bt;
        float v = 0.f;
        if (btg < BT) {
            int b = btg / NT, t = btg - b * NT;
            v = (d == 0) ? DT : X[((size_t)b * Sz + t + 1) * Dz + (d - 1)] * DT;
        }
        u_lds[d][bt] = v;
    }
    __syncthreads();

    const int o = obase + tid * 4;
    float4 acc[16];
#pragma unroll
    for (int bt = 0; bt < 16; ++bt) acc[bt] = make_float4(0.f, 0.f, 0.f, 0.f);

    for (int d = 0; d < KK; ++d) {
        float4 w = *(const float4*)(Wt + (size_t)d * OO + o);
        const float4* ur = (const float4*)&u_lds[d][0];
        float4 u0 = ur[0], u1 = ur[1], u2 = ur[2], u3 = ur[3];
        float uu[16] = {u0.x, u0.y, u0.z, u0.w, u1.x, u1.y, u1.z, u1.w,
                        u2.x, u2.y, u2.z, u2.w, u3.x, u3.y, u3.z, u3.w};
#pragma unroll
        for (int bt = 0; bt < 16; ++bt) {
            acc[bt].x += w.x * uu[bt];
            acc[bt].y += w.y * uu[bt];
            acc[bt].z += w.z * uu[bt];
            acc[bt].w += w.w * uu[bt];
        }
    }

#pragma unroll
    for (int bt = 0; bt < 16; ++bt) {
        int btg = btbase + bt;
        if (btg < BT)
            *(float4*)(As + (size_t)btg * OO + o) = acc[bt];
    }
}

// -------- sequential scan: one block per batch --------
// thread (i = tid>>3, p = tid&7): row i, j-chunk [p*16, p*16+16)
__global__ __launch_bounds__(1024) void k_scan(const float* __restrict__ As,
                                               const float* __restrict__ Bs,
                                               float* __restrict__ out) {
    const int b = blockIdx.x;
    const int tid = threadIdx.x;
    const int i = tid >> 3, p = tid & 7;
    __shared__ __align__(16) float y[2][Hz];

    if (tid < Hz) y[0][tid] = out[(size_t)b * Sz * Hz + tid];  // y0 from k_y0
    __syncthreads();

    const float4* Abase = (const float4*)(As + (size_t)b * NT * OO);
    const float* Bsb = Bs + (size_t)b * NT * Hz;
    float* outb = out + (size_t)b * Sz * Hz;
    const int off = i * 32 + p * 4;  // float4 index of this thread's 16 A elems

    float4 n0 = Abase[off], n1 = Abase[off + 1], n2 = Abase[off + 2],
           n3 = Abase[off + 3];

    for (int t = 0; t < NT; ++t) {
        float4 a0 = n0, a1 = n1, a2 = n2, a3 = n3;
        if (t + 1 < NT) {
            const float4* An = Abase + (size_t)(t + 1) * (OO / 4) + off;
            n0 = An[0]; n1 = An[1]; n2 = An[2]; n3 = An[3];
        }
        const int cur = t & 1;
        const float4* yv = (const float4*)&y[cur][p * 16];
        float4 y0v = yv[0], y1v = yv[1], y2v = yv[2], y3v = yv[3];

        float s = a0.x * y0v.x + a0.y * y0v.y + a0.z * y0v.z + a0.w * y0v.w;
        s += a1.x * y1v.x + a1.y * y1v.y + a1.z * y1v.z + a1.w * y1v.w;
        s += a2.x * y2v.x + a2.y * y2v.y + a2.z * y2v.z + a2.w * y2v.w;
        s += a3.x * y3v.x + a3.y * y3v.y + a3.z * y3v.z + a3.w * y3v.w;
        s += __shfl_xor(s, 1);
        s += __shfl_xor(s, 2);
        s += __shfl_xor(s, 4);

        if (p == 0) {
            float st = s + Bsb[(size_t)t * Hz + i];
            float yn = y[cur][i] + st;           // tanh skipped (see header)
            y[cur ^ 1][i] = yn;
            outb[(size_t)(t + 1) * Hz + i] = yn;
        }
        __syncthreads();
    }
}

// -------- fallback (ws too small): fused slow scan, A on the fly --------
__global__ __launch_bounds__(1024) void k_fused(const float* __restrict__ X,
                                                const float* __restrict__ initW,
                                                const float* __restrict__ initb,
                                                const float* __restrict__ WA,
                                                const float* __restrict__ WB,
                                                float* __restrict__ out) {
    const int b = blockIdx.x, tid = threadIdx.x;
    const int i = tid >> 3, p = tid & 7;
    __shared__ float y[2][Hz];
    __shared__ float u[KK];

    if (tid < Hz) {
        float a = initb[tid];
        const float* xr = X + (size_t)b * Sz * Dz;
        const float* wr = initW + (size_t)tid * Dz;
        for (int d = 0; d < Dz; ++d) a += xr[d] * wr[d];
        y[0][tid] = a;
        out[(size_t)b * Sz * Hz + tid] = a;
    }
    __syncthreads();

    for (int t = 0; t < NT; ++t) {
        if (tid < KK)
            u[tid] = (tid == 0) ? DT
                               : X[((size_t)b * Sz + t + 1) * Dz + tid - 1] * DT;
        __syncthreads();
        const int cur = t & 1;
        float partial = 0.f;
        for (int jj = 0; jj < 16; ++jj) {
            int j = p * 16 + jj;
            const float* wr = WA + (size_t)(i * Hz + j) * KK;
            float a = 0.f;
            for (int d = 0; d < KK; ++d) a += wr[d] * u[d];
            partial += a * y[cur][j];
        }
        partial += __shfl_xor(partial, 1);
        partial += __shfl_xor(partial, 2);
        partial += __shfl_xor(partial, 4);
        if (p == 0) {
            const float* wb = WB + (size_t)i * KK;
            float bv = 0.f;
            for (int d = 0; d < KK; ++d) bv += wb[d] * u[d];
            float yn = y[cur][i] + partial + bv;
            y[cur ^ 1][i] = yn;
            out[(size_t)b * Sz * Hz + (size_t)(t + 1) * Hz + i] = yn;
        }
        __syncthreads();
    }
}

extern "C" void kernel_launch(void* const* d_in, const int* in_sizes, int n_in,
                              void* d_out, int out_size, void* d_ws,
                              size_t ws_size, hipStream_t stream) {
    const float* X = (const float*)d_in[0];
    const float* initW = (const float*)d_in[1];
    const float* initb = (const float*)d_in[2];
    const float* WA = (const float*)d_in[3];
    const float* WB = (const float*)d_in[4];
    float* out = (float*)d_out;

    if (ws_size >= WS_NEED) {
        float* Wt = (float*)((char*)d_ws + WT_OFF);
        float* Bs = (float*)((char*)d_ws + BS_OFF);
        float* As = (float*)((char*)d_ws + AS_OFF);
        k_wt<<<64, 256, 0, stream>>>(WA, Wt);
        k_y0<<<4, 256, 0, stream>>>(X, initW, initb, out);
        k_bs<<<2044, 256, 0, stream>>>(X, WB, Bs);
        k_gemm<<<dim3(16, 256), 256, 0, stream>>>(X, Wt, As);
        k_scan<<<Bz, 1024, 0, stream>>>(As, Bs, out);
    } else {
        k_fused<<<Bz, 1024, 0, stream>>>(X, initW, initb, WA, WB, out);
    }
}

// Round 2
// 562.002 us; speedup vs baseline: 103.0341x; 103.0341x over previous
//
#include <hip/hip_runtime.h>
#include <hip/hip_bf16.h>

// LinearCDE: y_{t+1} = y_t + A_t y_t + b_t, A_t = reshape(vf_A_W @ u_t, HxH),
// u_t = [1, X[:,t+1]] * DT.  CLIP=1e11 => CLIP*tanh(st/CLIP) == st to ~1e-10
// relative, so tanh is skipped.
//
// Round-1 change: ws-adaptive time-slicing (fallback ran last round because
// ws < 274 MB), As stored in bf16 (halves scan bytes), depth-2 A prefetch.
//
// B=8 S=512 D=64 H=128.
#define DT 0.025f
#define Bz 8
#define Sz 512
#define Dz 64
#define Hz 128
#define NT 511            // S-1 time steps in the scan
#define OO (Hz * Hz)      // 16384 rows of vf_A_W
#define KK (Dz + 1)       // 65

typedef unsigned short ushort8v __attribute__((ext_vector_type(8)));
typedef unsigned short ushort4v __attribute__((ext_vector_type(4)));

__device__ __forceinline__ float bf2f(unsigned short u) {
    union { unsigned int i; float f; } v;
    v.i = ((unsigned int)u) << 16;
    return v.f;
}
__device__ __forceinline__ unsigned short f2bf(float f) {
    union { float f; unsigned int i; } v;
    v.f = f;
    unsigned int u = v.i;
    return (unsigned short)((u + 0x7FFFu + ((u >> 16) & 1u)) >> 16);  // RNE
}

// -------- transpose vf_A_W (o,d) -> Wt (d,o), coalesced writes --------
__global__ __launch_bounds__(256) void k_wt(const float* __restrict__ WA,
                                            float* __restrict__ Wt) {
    int o = blockIdx.x * 256 + threadIdx.x;           // 64 blocks
    const float* row = WA + (size_t)o * KK;
    for (int d = 0; d < KK; ++d)
        Wt[(size_t)d * OO + o] = row[d];
}

// -------- y0 = X[:,0] @ init_W^T + init_b, write to out[:,0,:] --------
__global__ __launch_bounds__(256) void k_y0(const float* __restrict__ X,
                                            const float* __restrict__ W,
                                            const float* __restrict__ bias,
                                            float* __restrict__ out) {
    int idx = blockIdx.x * 256 + threadIdx.x;         // 4 blocks, 1024 total
    int b = idx >> 7, h = idx & 127;
    const float* xr = X + (size_t)b * Sz * Dz;        // X[b,0,:]
    const float* wr = W + (size_t)h * Dz;
    float acc = bias[h];
    for (int d = 0; d < Dz; ++d) acc += xr[d] * wr[d];
    out[(size_t)b * Sz * Hz + h] = acc;
}

// -------- Bs[bt,h] = DT * (WB[h,0] + sum_k X[b,t+1,k] * WB[h,1+k]) --------
__global__ __launch_bounds__(256) void k_bs(const float* __restrict__ X,
                                            const float* __restrict__ WB,
                                            float* __restrict__ Bs) {
    int idx = blockIdx.x * 256 + threadIdx.x;         // 2044 blocks
    int bt = idx >> 7, h = idx & 127;
    int b = bt / NT, t = bt - b * NT;
    const float* xr = X + ((size_t)b * Sz + t + 1) * Dz;
    const float* wr = WB + (size_t)h * KK;
    float acc = wr[0];
    for (int k = 0; k < Dz; ++k) acc += xr[k] * wr[1 + k];
    Bs[(size_t)bt * Hz + h] = acc * DT;
}

// -------- As slice GEMM: As[m, o] = bf16( sum_d u[m,d] * Wt[d, o] ) --------
// row m = b*Ls + lt  (t = t0+lt), M = 8*Ls rows. tile: 16 m x 1024 o / block.
__global__ __launch_bounds__(256) void k_gemm_slice(
    const float* __restrict__ X, const float* __restrict__ Wt,
    unsigned short* __restrict__ As, int t0, int Ls) {
    __shared__ __align__(16) float u_lds[KK][16];
    const int tid = threadIdx.x;
    const int obase = blockIdx.x * 1024;              // 16 o-tiles
    const int rbase = blockIdx.y * 16;
    const int M = Bz * Ls;

    for (int idx = tid; idx < KK * 16; idx += 256) {
        int d = idx >> 4, r = idx & 15;
        int m = rbase + r;
        float v = 0.f;
        if (m < M) {
            int b = m / Ls, lt = m - b * Ls;
            int t = t0 + lt;
            v = (d == 0) ? DT : X[((size_t)b * Sz + t + 1) * Dz + (d - 1)] * DT;
        }
        u_lds[d][r] = v;
    }
    __syncthreads();

    const int o = obase + tid * 4;
    float4 acc[16];
#pragma unroll
    for (int r = 0; r < 16; ++r) acc[r] = make_float4(0.f, 0.f, 0.f, 0.f);

    for (int d = 0; d < KK; ++d) {
        float4 w = *(const float4*)(Wt + (size_t)d * OO + o);
        const float4* ur = (const float4*)&u_lds[d][0];
        float4 u0 = ur[0], u1 = ur[1], u2 = ur[2], u3 = ur[3];
        float uu[16] = {u0.x, u0.y, u0.z, u0.w, u1.x, u1.y, u1.z, u1.w,
                        u2.x, u2.y, u2.z, u2.w, u3.x, u3.y, u3.z, u3.w};
#pragma unroll
        for (int r = 0; r < 16; ++r) {
            acc[r].x += w.x * uu[r];
            acc[r].y += w.y * uu[r];
            acc[r].z += w.z * uu[r];
            acc[r].w += w.w * uu[r];
        }
    }

#pragma unroll
    for (int r = 0; r < 16; ++r) {
        int m = rbase + r;
        if (m < M) {
            ushort4v pk;
            pk[0] = f2bf(acc[r].x); pk[1] = f2bf(acc[r].y);
            pk[2] = f2bf(acc[r].z); pk[3] = f2bf(acc[r].w);
            *(ushort4v*)(As + (size_t)m * OO + o) = pk;
        }
    }
}

// -------- sequential scan over one slice: one block per batch --------
// thread (i = tid>>3, p = tid&7): row i, j-chunk [p*16, p*16+16)
__global__ __launch_bounds__(1024) void k_scan_slice(
    const unsigned short* __restrict__ As, const float* __restrict__ Bs,
    float* __restrict__ out, int t0, int Ls) {
    const int b = blockIdx.x;
    const int tid = threadIdx.x;
    const int i = tid >> 3, p = tid & 7;
    __shared__ __align__(16) float y[2][Hz];

    if (tid < Hz) y[0][tid] = out[((size_t)b * Sz + t0) * Hz + tid];
    __syncthreads();

    const unsigned short* Ab = As + (size_t)b * Ls * OO + i * Hz + p * 16;
    const float* Bsb = Bs + (size_t)b * NT * Hz;
    float* outb = out + (size_t)b * Sz * Hz;

    // depth-2 prefetch ring: c = step lt, d = step lt+1
    ushort8v c0 = *(const ushort8v*)(Ab);
    ushort8v c1 = *(const ushort8v*)(Ab + 8);
    int l1 = (Ls > 1) ? 1 : 0;
    ushort8v d0 = *(const ushort8v*)(Ab + (size_t)l1 * OO);
    ushort8v d1 = *(const ushort8v*)(Ab + (size_t)l1 * OO + 8);

    for (int lt = 0; lt < Ls; ++lt) {
        int ln = lt + 2; if (ln > Ls - 1) ln = Ls - 1;
        ushort8v e0 = *(const ushort8v*)(Ab + (size_t)ln * OO);
        ushort8v e1 = *(const ushort8v*)(Ab + (size_t)ln * OO + 8);

        const int cur = lt & 1;
        const float4* yv = (const float4*)&y[cur][p * 16];
        float4 y0v = yv[0], y1v = yv[1], y2v = yv[2], y3v = yv[3];

        float s;
        s  = bf2f(c0[0]) * y0v.x + bf2f(c0[1]) * y0v.y +
             bf2f(c0[2]) * y0v.z + bf2f(c0[3]) * y0v.w;
        s += bf2f(c0[4]) * y1v.x + bf2f(c0[5]) * y1v.y +
             bf2f(c0[6]) * y1v.z + bf2f(c0[7]) * y1v.w;
        s += bf2f(c1[0]) * y2v.x + bf2f(c1[1]) * y2v.y +
             bf2f(c1[2]) * y2v.z + bf2f(c1[3]) * y2v.w;
        s += bf2f(c1[4]) * y3v.x + bf2f(c1[5]) * y3v.y +
             bf2f(c1[6]) * y3v.z + bf2f(c1[7]) * y3v.w;
        s += __shfl_xor(s, 1);
        s += __shfl_xor(s, 2);
        s += __shfl_xor(s, 4);

        if (p == 0) {
            float st = s + Bsb[(size_t)(t0 + lt) * Hz + i];
            float yn = y[cur][i] + st;           // tanh skipped (see header)
            y[cur ^ 1][i] = yn;
            outb[(size_t)(t0 + lt + 1) * Hz + i] = yn;
        }
        c0 = d0; c1 = d1; d0 = e0; d1 = e1;
        __syncthreads();
    }
}

// -------- fallback (ws tiny): fused slow scan, A on the fly --------
__global__ __launch_bounds__(1024) void k_fused(const float* __restrict__ X,
                                                const float* __restrict__ initW,
                                                const float* __restrict__ initb,
                                                const float* __restrict__ WA,
                                                const float* __restrict__ WB,
                                                float* __restrict__ out) {
    const int b = blockIdx.x, tid = threadIdx.x;
    const int i = tid >> 3, p = tid & 7;
    __shared__ float y[2][Hz];
    __shared__ float u[KK];

    if (tid < Hz) {
        float a = initb[tid];
        const float* xr = X + (size_t)b * Sz * Dz;
        const float* wr = initW + (size_t)tid * Dz;
        for (int d = 0; d < Dz; ++d) a += xr[d] * wr[d];
        y[0][tid] = a;
        out[(size_t)b * Sz * Hz + tid] = a;
    }
    __syncthreads();

    for (int t = 0; t < NT; ++t) {
        if (tid < KK)
            u[tid] = (tid == 0) ? DT
                               : X[((size_t)b * Sz + t + 1) * Dz + tid - 1] * DT;
        __syncthreads();
        const int cur = t & 1;
        float partial = 0.f;
        for (int jj = 0; jj < 16; ++jj) {
            int j = p * 16 + jj;
            const float* wr = WA + (size_t)(i * Hz + j) * KK;
            float a = 0.f;
            for (int d = 0; d < KK; ++d) a += wr[d] * u[d];
            partial += a * y[cur][j];
        }
        partial += __shfl_xor(partial, 1);
        partial += __shfl_xor(partial, 2);
        partial += __shfl_xor(partial, 4);
        if (p == 0) {
            const float* wb = WB + (size_t)i * KK;
            float bv = 0.f;
            for (int d = 0; d < KK; ++d) bv += wb[d] * u[d];
            float yn = y[cur][i] + partial + bv;
            y[cur ^ 1][i] = yn;
            out[(size_t)b * Sz * Hz + (size_t)(t + 1) * Hz + i] = yn;
        }
        __syncthreads();
    }
}

extern "C" void kernel_launch(void* const* d_in, const int* in_sizes, int n_in,
                              void* d_out, int out_size, void* d_ws,
                              size_t ws_size, hipStream_t stream) {
    const float* X = (const float*)d_in[0];
    const float* initW = (const float*)d_in[1];
    const float* initb = (const float*)d_in[2];
    const float* WA = (const float*)d_in[3];
    const float* WB = (const float*)d_in[4];
    float* out = (float*)d_out;

    const size_t WT_BYTES = (size_t)KK * OO * 4;          // 4,259,840
    const size_t BS_BYTES = (size_t)Bz * NT * Hz * 4;     // 2,093,056
    const size_t BASE = WT_BYTES + BS_BYTES;              // 6,352,896
    const size_t ROW_BYTES = (size_t)OO * 2;              // 32 KB per (b,t), bf16

    if (ws_size >= BASE + (size_t)Bz * ROW_BYTES * 8) {   // need at least Ls=8
        int Ls_max = (int)((ws_size - BASE) / ((size_t)Bz * ROW_BYTES));
        if (Ls_max > NT) Ls_max = NT;
        int nS = (NT + Ls_max - 1) / Ls_max;
        int Ls = (NT + nS - 1) / nS;                      // balanced slice len

        float* Wt = (float*)d_ws;
        float* Bs = (float*)((char*)d_ws + WT_BYTES);
        unsigned short* As = (unsigned short*)((char*)d_ws + BASE);

        k_wt<<<64, 256, 0, stream>>>(WA, Wt);
        k_y0<<<4, 256, 0, stream>>>(X, initW, initb, out);
        k_bs<<<2044, 256, 0, stream>>>(X, WB, Bs);

        for (int t0 = 0; t0 < NT; t0 += Ls) {
            int Lse = NT - t0 < Ls ? NT - t0 : Ls;
            int M = Bz * Lse;
            dim3 grid(16, (M + 15) / 16);
            k_gemm_slice<<<grid, 256, 0, stream>>>(X, Wt, As, t0, Lse);
            k_scan_slice<<<Bz, 1024, 0, stream>>>(As, Bs, out, t0, Lse);
        }
    } else {
        k_fused<<<Bz, 1024, 0, stream>>>(X, initW, initb, WA, WB, out);
    }
}

// Round 3
// 465.029 us; speedup vs baseline: 124.5200x; 1.2085x over previous
//
#include <hip/hip_runtime.h>
#include <hip/hip_bf16.h>

// LinearCDE: y_{t+1} = y_t + A_t y_t + b_t, A_t = reshape(vf_A_W @ u_t, HxH),
// u_t = [1, X[:,t+1]] * DT.  CLIP=1e11 => tanh is identity to ~1e-10 rel.
//
// Round-2 change: chunked associative scan. Per 16-step chunk c:
//   y_end = (I + Delta_c) y_start + v_c,
//   Delta_k = Delta_{k-1} + A_k @ (I + Delta_{k-1})   (bf16 MFMA, fp32 accum)
//   v_k     = v_{k-1} + A_k @ v_{k-1} + b_k
// Stage a: 256 parallel chunk-workgroups (MFMA). Stage b: short sequential
// scan over chunks. Stage c: parallel 16-step replay for interior rows.
#define DT 0.025f
#define Bz 8
#define Sz 512
#define Dz 64
#define Hz 128
#define NT 511            // S-1 steps
#define OO (Hz * Hz)      // 16384
#define KK (Dz + 1)       // 65
#define CHUNK 16

using short8 = __attribute__((ext_vector_type(8))) short;
using f32x4  = __attribute__((ext_vector_type(4))) float;
using u16x8  = __attribute__((ext_vector_type(8))) unsigned short;
using u16x4  = __attribute__((ext_vector_type(4))) unsigned short;

__device__ __forceinline__ float bf2f(unsigned short u) {
    union { unsigned int i; float f; } v;
    v.i = ((unsigned int)u) << 16;
    return v.f;
}
__device__ __forceinline__ unsigned short f2bf(float f) {
    union { float f; unsigned int i; } v;
    v.f = f;
    unsigned int u = v.i;
    return (unsigned short)((u + 0x7FFFu + ((u >> 16) & 1u)) >> 16);  // RNE
}

// -------- transpose vf_A_W (o,d) -> Wt (d,o), LDS-tiled --------
__global__ __launch_bounds__(256) void k_wt(const float* __restrict__ WA,
                                            float* __restrict__ Wt) {
    __shared__ float T[64][66];
    const int tid = threadIdx.x;
    const int o0 = blockIdx.x * 64;                   // 256 blocks
    for (int idx = tid; idx < 64 * KK; idx += 256) {
        int r = idx / KK, c = idx - r * KK;
        T[r][c] = WA[(size_t)(o0 + r) * KK + c];
    }
    __syncthreads();
    for (int idx = tid; idx < KK * 64; idx += 256) {
        int d = idx >> 6, o = idx & 63;
        Wt[(size_t)d * OO + o0 + o] = T[o][d];
    }
}

// -------- y0 = X[:,0] @ init_W^T + init_b --------
__global__ __launch_bounds__(256) void k_y0(const float* __restrict__ X,
                                            const float* __restrict__ W,
                                            const float* __restrict__ bias,
                                            float* __restrict__ out) {
    int idx = blockIdx.x * 256 + threadIdx.x;
    int b = idx >> 7, h = idx & 127;
    const float* xr = X + (size_t)b * Sz * Dz;
    const float* wr = W + (size_t)h * Dz;
    float acc = bias[h];
    for (int d = 0; d < Dz; ++d) acc += xr[d] * wr[d];
    out[(size_t)b * Sz * Hz + h] = acc;
}

// -------- Bs[bt,h] --------
__global__ __launch_bounds__(256) void k_bs(const float* __restrict__ X,
                                            const float* __restrict__ WB,
                                            float* __restrict__ Bs) {
    int idx = blockIdx.x * 256 + threadIdx.x;
    int bt = idx >> 7, h = idx & 127;
    int b = bt / NT, t = bt - b * NT;
    const float* xr = X + ((size_t)b * Sz + t + 1) * Dz;
    const float* wr = WB + (size_t)h * KK;
    float acc = wr[0];
    for (int k = 0; k < Dz; ++k) acc += xr[k] * wr[1 + k];
    Bs[(size_t)bt * Hz + h] = acc * DT;
}

// -------- As slice GEMM (fp32 VALU, bf16 out) --------
__global__ __launch_bounds__(256) void k_gemm_slice(
    const float* __restrict__ X, const float* __restrict__ Wt,
    unsigned short* __restrict__ As, int t0, int Ls) {
    __shared__ __align__(16) float u_lds[KK][16];
    const int tid = threadIdx.x;
    const int obase = blockIdx.x * 1024;
    const int rbase = blockIdx.y * 16;
    const int M = Bz * Ls;

    for (int idx = tid; idx < KK * 16; idx += 256) {
        int d = idx >> 4, r = idx & 15;
        int m = rbase + r;
        float v = 0.f;
        if (m < M) {
            int b = m / Ls, lt = m - b * Ls;
            int t = t0 + lt;
            v = (d == 0) ? DT : X[((size_t)b * Sz + t + 1) * Dz + (d - 1)] * DT;
        }
        u_lds[d][r] = v;
    }
    __syncthreads();

    const int o = obase + tid * 4;
    float4 acc[16];
#pragma unroll
    for (int r = 0; r < 16; ++r) acc[r] = make_float4(0.f, 0.f, 0.f, 0.f);

    for (int d = 0; d < KK; ++d) {
        float4 w = *(const float4*)(Wt + (size_t)d * OO + o);
        const float4* ur = (const float4*)&u_lds[d][0];
        float4 u0 = ur[0], u1 = ur[1], u2 = ur[2], u3 = ur[3];
        float uu[16] = {u0.x, u0.y, u0.z, u0.w, u1.x, u1.y, u1.z, u1.w,
                        u2.x, u2.y, u2.z, u2.w, u3.x, u3.y, u3.z, u3.w};
#pragma unroll
        for (int r = 0; r < 16; ++r) {
            acc[r].x += w.x * uu[r];
            acc[r].y += w.y * uu[r];
            acc[r].z += w.z * uu[r];
            acc[r].w += w.w * uu[r];
        }
    }

#pragma unroll
    for (int r = 0; r < 16; ++r) {
        int m = rbase + r;
        if (m < M) {
            u16x4 pk;
            pk[0] = f2bf(acc[r].x); pk[1] = f2bf(acc[r].y);
            pk[2] = f2bf(acc[r].z); pk[3] = f2bf(acc[r].w);
            *(u16x4*)(As + (size_t)m * OO + o) = pk;
        }
    }
}

// -------- stage a: per-chunk Delta (128x128) and v via MFMA --------
// grid (NCs, Bz), 512 threads = 8 waves (2x4 wave grid).
// Wave (wr,wc): 8 Delta tiles (ti=4wr+tix, tj=2wc+tjx) + v tile (ti=w).
// Pt LDS: P^T (= (I+Delta)^T) rows 0..127, row 128 = v; XOR-swizzled rows.
__global__ __launch_bounds__(512) void k_chunk_a(
    const unsigned short* __restrict__ As, const float* __restrict__ Bs,
    float* __restrict__ Dm, float* __restrict__ Vv,
    int t0, int Lsteps, int NCs) {
    const int cs = blockIdx.x, b = blockIdx.y;
    const int tid = threadIdx.x;
    const int w = tid >> 6, l = tid & 63;
    const int lr = l & 15, lg = l >> 4;
    const int wr = w >> 2, wc = w & 3;
    int Lc = Lsteps - cs * CHUNK; if (Lc > CHUNK) Lc = CHUNK;

    __shared__ __align__(16) unsigned short Abuf[2][OO];   // 2 x 32KB swizzled
    __shared__ __align__(16) unsigned short Pt[129 * Hz];  // 33KB swizzled

    // init Pt = [I ; v=0]
    for (int idx = tid; idx < 129 * Hz; idx += 512) {
        int row = idx >> 7, col = idx & 127;
        unsigned short val = (row < Hz && row == col) ? (unsigned short)0x3F80
                                                      : (unsigned short)0;
        int unit = (col >> 3) ^ (row & 7);
        Pt[(row << 7) | (unit << 3) | (col & 7)] = val;
    }

    const unsigned short* Ab = As + ((size_t)b * Lsteps + cs * CHUNK) * OO;

    // stage step 0 into Abuf[0] (swizzled dest via linear-dest/swizzled-src)
    {
        const u16x8* src = (const u16x8*)Ab;
#pragma unroll
        for (int rr = 0; rr < 4; ++rr) {
            int du = tid + rr * 512;
            int row = du >> 4, cu = du & 15;
            int su = (du & ~15) | (cu ^ (row & 7));
            u16x8 v = src[su];
            *(u16x8*)&Abuf[0][du << 3] = v;
        }
    }

    f32x4 acc[9] = {};          // 8 Delta tiles + v tile, fp32, persist
    const int kxor = lr & 7;

    for (int k = 0; k < Lc; ++k) {
        __syncthreads();        // Pt + Abuf[cur] ready
        const int cur = k & 1;

        // prefetch A for step k+1 into regs
        u16x8 nx0, nx1, nx2, nx3;
        if (k + 1 < Lc) {
            const u16x8* src = (const u16x8*)(Ab + (size_t)(k + 1) * OO);
            int du0 = tid, du1 = tid + 512, du2 = tid + 1024, du3 = tid + 1536;
            nx0 = src[(du0 & ~15) | ((du0 & 15) ^ ((du0 >> 4) & 7))];
            nx1 = src[(du1 & ~15) | ((du1 & 15) ^ ((du1 >> 4) & 7))];
            nx2 = src[(du2 & ~15) | ((du2 & 15) ^ ((du2 >> 4) & 7))];
            nx3 = src[(du3 & ~15) | ((du3 & 15) ^ ((du3 >> 4) & 7))];
        }
        // bias for v tile
        const int t = t0 + cs * CHUNK + k;
        float bsv0 = 0.f, bsv1 = 0.f, bsv2 = 0.f, bsv3 = 0.f;
        if (lr == 0) {
            const float* bp = Bs + ((size_t)b * NT + t) * Hz + 16 * w + 4 * lg;
            bsv0 = bp[0]; bsv1 = bp[1]; bsv2 = bp[2]; bsv3 = bp[3];
        }

#pragma unroll
        for (int kt = 0; kt < 4; ++kt) {
            const int uoff = ((kt * 4 + lg) ^ kxor) << 3;
            short8 af[4];
#pragma unroll
            for (int tix = 0; tix < 4; ++tix) {
                int r = 64 * wr + 16 * tix + lr;
                af[tix] = *(const short8*)&Abuf[cur][(r << 7) | uoff];
            }
            short8 bf[2];
#pragma unroll
            for (int tjx = 0; tjx < 2; ++tjx) {
                int j = 32 * wc + 16 * tjx + lr;
                bf[tjx] = *(const short8*)&Pt[(j << 7) | uoff];
            }
            // v row (128): broadcast to all lanes (no swizzle: 128&7==0)
            short8 vf = *(const short8*)&Pt[(128 << 7) | ((kt * 4 + lg) << 3)];
#pragma unroll
            for (int tix = 0; tix < 4; ++tix) {
                acc[tix * 2 + 0] = __builtin_amdgcn_mfma_f32_16x16x32_bf16(
                    af[tix], bf[0], acc[tix * 2 + 0], 0, 0, 0);
                acc[tix * 2 + 1] = __builtin_amdgcn_mfma_f32_16x16x32_bf16(
                    af[tix], bf[1], acc[tix * 2 + 1], 0, 0, 0);
            }
            acc[8] = __builtin_amdgcn_mfma_f32_16x16x32_bf16(af[wc], vf,
                                                             acc[8], 0, 0, 0);
        }
        if (lr == 0) {
            acc[8][0] += bsv0; acc[8][1] += bsv1;
            acc[8][2] += bsv2; acc[8][3] += bsv3;
        }
        __syncthreads();        // all Pt/Abuf reads done

        // rewrite Pt = (I + Delta)^T in bf16
#pragma unroll
        for (int tix = 0; tix < 4; ++tix)
#pragma unroll
            for (int tjx = 0; tjx < 2; ++tjx) {
                int i0 = 64 * wr + 16 * tix + 4 * lg;
                int j = 32 * wc + 16 * tjx + lr;
                u16x4 pk;
#pragma unroll
                for (int r = 0; r < 4; ++r) {
                    float pv = acc[tix * 2 + tjx][r] + ((i0 + r) == j ? 1.f : 0.f);
                    pk[r] = f2bf(pv);
                }
                int unit = (i0 >> 3) ^ (j & 7);
                *(u16x4*)&Pt[(j << 7) | (unit << 3) | (i0 & 7)] = pk;
            }
        if (lr == 0) {
            int i0 = 16 * w + 4 * lg;
            u16x4 pk;
#pragma unroll
            for (int r = 0; r < 4; ++r) pk[r] = f2bf(acc[8][r]);
            *(u16x4*)&Pt[(128 << 7) | ((i0 >> 3) << 3) | (i0 & 7)] = pk;
        }
        // write staged A for next step
        if (k + 1 < Lc) {
            unsigned short* dst = Abuf[cur ^ 1];
            *(u16x8*)&dst[(tid) << 3] = nx0;
            *(u16x8*)&dst[(tid + 512) << 3] = nx1;
            *(u16x8*)&dst[(tid + 1024) << 3] = nx2;
            *(u16x8*)&dst[(tid + 1536) << 3] = nx3;
        }
    }

    // write Delta (fp32) and v to global
    const size_t ci = (size_t)b * NCs + cs;
    float* D = Dm + ci * OO;
#pragma unroll
    for (int tix = 0; tix < 4; ++tix)
#pragma unroll
        for (int tjx = 0; tjx < 2; ++tjx) {
            int i0 = 64 * wr + 16 * tix + 4 * lg;
            int j = 32 * wc + 16 * tjx + lr;
#pragma unroll
            for (int r = 0; r < 4; ++r)
                D[(size_t)(i0 + r) * Hz + j] = acc[tix * 2 + tjx][r];
        }
    if (lr == 0) {
        int i0 = 16 * w + 4 * lg;
        float* V = Vv + ci * Hz;
#pragma unroll
        for (int r = 0; r < 4; ++r) V[i0 + r] = acc[8][r];
    }
}

// -------- stage b: sequential over chunks, y_end = y + Delta y + v --------
__global__ __launch_bounds__(512) void k_chunk_b(
    const float* __restrict__ Dm, const float* __restrict__ Vv,
    float* __restrict__ out, int t0, int Lsteps, int NCs) {
    const int b = blockIdx.x, tid = threadIdx.x;
    const int q = tid >> 7, i = tid & 127;
    __shared__ float yv[Hz];
    __shared__ float part[4][Hz];

    if (tid < Hz) yv[tid] = out[((size_t)b * Sz + t0) * Hz + tid];
    __syncthreads();

    for (int cs = 0; cs < NCs; ++cs) {
        const size_t ci = (size_t)b * NCs + cs;
        const float4* Drow =
            (const float4*)(Dm + ci * OO + (size_t)i * Hz + q * 32);
        float s = 0.f;
#pragma unroll
        for (int v4 = 0; v4 < 8; ++v4) {
            float4 d = Drow[v4];
            const float* yp = &yv[q * 32 + v4 * 4];
            s += d.x * yp[0] + d.y * yp[1] + d.z * yp[2] + d.w * yp[3];
        }
        part[q][i] = s;
        __syncthreads();
        if (tid < Hz) {
            float yn = yv[tid] + part[0][tid] + part[1][tid] + part[2][tid] +
                       part[3][tid] + Vv[ci * Hz + tid];
            yv[tid] = yn;
            int t_end = t0 + (cs + 1) * CHUNK;
            if (t_end < Sz)
                out[((size_t)b * Sz + t_end) * Hz + tid] = yn;  // boundary row
        }
        __syncthreads();
    }
}

// -------- stage c: 16-step replay per chunk (interior rows) --------
__global__ __launch_bounds__(1024) void k_chunk_c(
    const unsigned short* __restrict__ As, const float* __restrict__ Bs,
    float* __restrict__ out, int t0, int Lsteps, int NCs) {
    const int cs = blockIdx.x, b = blockIdx.y;
    const int tid = threadIdx.x;
    const int i = tid >> 3, p = tid & 7;
    const int t0c = t0 + cs * CHUNK;
    int Lc = Lsteps - cs * CHUNK; if (Lc > CHUNK) Lc = CHUNK;
    __shared__ __align__(16) float y[2][Hz];

    if (tid < Hz) y[0][tid] = out[((size_t)b * Sz + t0c) * Hz + tid];
    __syncthreads();

    const unsigned short* Abp =
        As + ((size_t)b * Lsteps + cs * CHUNK) * OO + i * Hz + p * 16;
    const float* Bsb = Bs + (size_t)b * NT * Hz;
    float* outb = out + (size_t)b * Sz * Hz;

    u16x8 c0 = *(const u16x8*)(Abp);
    u16x8 c1 = *(const u16x8*)(Abp + 8);
    int l1 = (Lc > 1) ? 1 : 0;
    u16x8 d0 = *(const u16x8*)(Abp + (size_t)l1 * OO);
    u16x8 d1 = *(const u16x8*)(Abp + (size_t)l1 * OO + 8);

    for (int lt = 0; lt < Lc; ++lt) {
        int ln = lt + 2; if (ln > Lc - 1) ln = Lc - 1;
        u16x8 e0 = *(const u16x8*)(Abp + (size_t)ln * OO);
        u16x8 e1 = *(const u16x8*)(Abp + (size_t)ln * OO + 8);

        const int cur = lt & 1;
        const float4* yp = (const float4*)&y[cur][p * 16];
        float4 y0v = yp[0], y1v = yp[1], y2v = yp[2], y3v = yp[3];

        float s;
        s  = bf2f(c0[0]) * y0v.x + bf2f(c0[1]) * y0v.y +
             bf2f(c0[2]) * y0v.z + bf2f(c0[3]) * y0v.w;
        s += bf2f(c0[4]) * y1v.x + bf2f(c0[5]) * y1v.y +
             bf2f(c0[6]) * y1v.z + bf2f(c0[7]) * y1v.w;
        s += bf2f(c1[0]) * y2v.x + bf2f(c1[1]) * y2v.y +
             bf2f(c1[2]) * y2v.z + bf2f(c1[3]) * y2v.w;
        s += bf2f(c1[4]) * y3v.x + bf2f(c1[5]) * y3v.y +
             bf2f(c1[6]) * y3v.z + bf2f(c1[7]) * y3v.w;
        s += __shfl_xor(s, 1);
        s += __shfl_xor(s, 2);
        s += __shfl_xor(s, 4);

        if (p == 0) {
            int t = t0c + lt;
            float st = s + Bsb[(size_t)t * Hz + i];
            float yn = y[cur][i] + st;
            y[cur ^ 1][i] = yn;
            if (((t + 1) & (CHUNK - 1)) != 0)        // boundaries: stage b
                outb[(size_t)(t + 1) * Hz + i] = yn;
        }
        c0 = d0; c1 = d1; d0 = e0; d1 = e1;
        __syncthreads();
    }
}

// -------- fallback (ws tiny) --------
__global__ __launch_bounds__(1024) void k_fused(const float* __restrict__ X,
                                                const float* __restrict__ initW,
                                                const float* __restrict__ initb,
                                                const float* __restrict__ WA,
                                                const float* __restrict__ WB,
                                                float* __restrict__ out) {
    const int b = blockIdx.x, tid = threadIdx.x;
    const int i = tid >> 3, p = tid & 7;
    __shared__ float y[2][Hz];
    __shared__ float u[KK];

    if (tid < Hz) {
        float a = initb[tid];
        const float* xr = X + (size_t)b * Sz * Dz;
        const float* wr = initW + (size_t)tid * Dz;
        for (int d = 0; d < Dz; ++d) a += xr[d] * wr[d];
        y[0][tid] = a;
        out[(size_t)b * Sz * Hz + tid] = a;
    }
    __syncthreads();

    for (int t = 0; t < NT; ++t) {
        if (tid < KK)
            u[tid] = (tid == 0) ? DT
                                : X[((size_t)b * Sz + t + 1) * Dz + tid - 1] * DT;
        __syncthreads();
        const int cur = t & 1;
        float partial = 0.f;
        for (int jj = 0; jj < 16; ++jj) {
            int j = p * 16 + jj;
            const float* wr = WA + (size_t)(i * Hz + j) * KK;
            float a = 0.f;
            for (int d = 0; d < KK; ++d) a += wr[d] * u[d];
            partial += a * y[cur][j];
        }
        partial += __shfl_xor(partial, 1);
        partial += __shfl_xor(partial, 2);
        partial += __shfl_xor(partial, 4);
        if (p == 0) {
            const float* wb = WB + (size_t)i * KK;
            float bv = 0.f;
            for (int d = 0; d < KK; ++d) bv += wb[d] * u[d];
            float yn = y[cur][i] + partial + bv;
            y[cur ^ 1][i] = yn;
            out[(size_t)b * Sz * Hz + (size_t)(t + 1) * Hz + i] = yn;
        }
        __syncthreads();
    }
}

extern "C" void kernel_launch(void* const* d_in, const int* in_sizes, int n_in,
                              void* d_out, int out_size, void* d_ws,
                              size_t ws_size, hipStream_t stream) {
    const float* X = (const float*)d_in[0];
    const float* initW = (const float*)d_in[1];
    const float* initb = (const float*)d_in[2];
    const float* WA = (const float*)d_in[3];
    const float* WB = (const float*)d_in[4];
    float* out = (float*)d_out;

    const size_t WT_BYTES = (size_t)KK * OO * 4;      // 4,259,840
    const size_t BS_BYTES = (size_t)Bz * NT * Hz * 4; // 2,093,056
    const size_t base = WT_BYTES + BS_BYTES;
    // per-chunk-column bytes: As 8*16*32KB + Dm 8*64KB + Vv 8*512B
    const size_t PER_SC = (size_t)Bz * CHUNK * OO * 2 + (size_t)Bz * OO * 4 +
                          (size_t)Bz * Hz * 4;        // 4,722,688
    const int NC = (NT + CHUNK - 1) / CHUNK;          // 32

    long SC_max = (ws_size > base) ? (long)((ws_size - base) / PER_SC) : 0;
    if (SC_max >= 1) {
        if (SC_max > NC) SC_max = NC;
        int nS = (NC + (int)SC_max - 1) / (int)SC_max;
        int SC = (NC + nS - 1) / nS;

        float* Wt = (float*)d_ws;
        float* Bs = (float*)((char*)d_ws + WT_BYTES);
        float* Dm = (float*)((char*)d_ws + base);
        float* Vv = (float*)((char*)d_ws + base + (size_t)SC * Bz * OO * 4);
        unsigned short* As = (unsigned short*)((char*)d_ws + base +
                                               (size_t)SC * Bz * OO * 4 +
                                               (size_t)SC * Bz * Hz * 4);

        k_wt<<<OO / 64, 256, 0, stream>>>(WA, Wt);
        k_y0<<<4, 256, 0, stream>>>(X, initW, initb, out);
        k_bs<<<2044, 256, 0, stream>>>(X, WB, Bs);

        for (int c0 = 0; c0 < NC; c0 += SC) {
            int t0 = c0 * CHUNK;
            int Lsteps = NT - t0;
            if (Lsteps > SC * CHUNK) Lsteps = SC * CHUNK;
            int NCs = (Lsteps + CHUNK - 1) / CHUNK;
            int M = Bz * Lsteps;
            k_gemm_slice<<<dim3(16, (M + 15) / 16), 256, 0, stream>>>(
                X, Wt, As, t0, Lsteps);
            k_chunk_a<<<dim3(NCs, Bz), 512, 0, stream>>>(As, Bs, Dm, Vv, t0,
                                                         Lsteps, NCs);
            k_chunk_b<<<Bz, 512, 0, stream>>>(Dm, Vv, out, t0, Lsteps, NCs);
            k_chunk_c<<<dim3(NCs, Bz), 1024, 0, stream>>>(As, Bs, out, t0,
                                                          Lsteps, NCs);
        }
    } else {
        k_fused<<<Bz, 1024, 0, stream>>>(X, initW, initb, WA, WB, out);
    }
}

// Round 4
// 243.462 us; speedup vs baseline: 237.8414x; 1.9101x over previous
//
#include <hip/hip_runtime.h>
#include <hip/hip_bf16.h>

// LinearCDE: y_{t+1} = y_t + A_t y_t + b_t, A_t = reshape(vf_A_W @ u_t, HxH),
// u_t = [1, X[:,t+1]] * DT.  CLIP=1e11 => tanh is identity to ~1e-10 rel.
//
// Round-3 changes: (1) chunk_a: 16 waves, global_load_lds ring-3 A staging
// with counted vmcnt(2) + raw s_barrier (no per-step vmcnt(0) drain), Bs in
// LDS, precomputed identity addend. (2) As GEMM on MFMA with bf16 2-term
// split (numerically ~fp32). (3) chunk_b register prefetch ring.
#define DT 0.025f
#define Bz 8
#define Sz 512
#define Dz 64
#define Hz 128
#define NT 511            // S-1 steps
#define OO (Hz * Hz)      // 16384
#define KK (Dz + 1)       // 65
#define CHUNK 16

using short8 = __attribute__((ext_vector_type(8))) short;
using f32x4  = __attribute__((ext_vector_type(4))) float;
using u16x8  = __attribute__((ext_vector_type(8))) unsigned short;
using u16x4  = __attribute__((ext_vector_type(4))) unsigned short;

__device__ __forceinline__ float bf2f(unsigned short u) {
    union { unsigned int i; float f; } v;
    v.i = ((unsigned int)u) << 16;
    return v.f;
}
__device__ __forceinline__ unsigned short f2bf(float f) {
    union { float f; unsigned int i; } v;
    v.f = f;
    unsigned int u = v.i;
    return (unsigned short)((u + 0x7FFFu + ((u >> 16) & 1u)) >> 16);  // RNE
}

// async 16B global -> LDS (dest: wave-uniform base + lane*16)
__device__ __forceinline__ void dma16(const void* g, void* s) {
    __builtin_amdgcn_global_load_lds(
        (const __attribute__((address_space(1))) unsigned int*)g,
        (__attribute__((address_space(3))) unsigned int*)s, 16, 0, 0);
}

// -------- split vf_A_W: Wh/Wl bf16 [o][64] (d=1..64), WA0d = DT*col0 --------
__global__ __launch_bounds__(256) void k_wsplit(const float* __restrict__ WA,
                                                unsigned short* __restrict__ Wh,
                                                unsigned short* __restrict__ Wl,
                                                float* __restrict__ WA0d) {
    int idx = blockIdx.x * 256 + threadIdx.x;   // 512 blocks: 16384 o x 8 units
    int o = idx >> 3, u = idx & 7;
    const float* wr = WA + (size_t)o * KK + 1 + u * 8;
    u16x8 h = {}, lo = {};
#pragma unroll
    for (int j = 0; j < 8; ++j) {
        float v = wr[j];
        unsigned short hh = f2bf(v);
        h[j] = hh;
        lo[j] = f2bf(v - bf2f(hh));
    }
    *(u16x8*)(Wh + (size_t)o * 64 + u * 8) = h;
    *(u16x8*)(Wl + (size_t)o * 64 + u * 8) = lo;
    if (u == 0) WA0d[o] = DT * WA[(size_t)o * KK];
}

// -------- per-slice u split: Xh/Xl bf16 [m][64], m = b*Lsteps+lt, pad 0 -----
__global__ __launch_bounds__(256) void k_prep(const float* __restrict__ X,
                                              unsigned short* __restrict__ Xh,
                                              unsigned short* __restrict__ Xl,
                                              int t0, int Lsteps) {
    int idx = blockIdx.x * 256 + threadIdx.x;   // 128 blocks: 4096 m x 8 units
    int m = idx >> 3, u = idx & 7;
    int Mr = Bz * Lsteps;
    u16x8 h = {}, lo = {};
    if (m < Mr) {
        int b = m / Lsteps, lt = m - b * Lsteps;
        const float* xr = X + ((size_t)b * Sz + t0 + lt + 1) * Dz + u * 8;
#pragma unroll
        for (int j = 0; j < 8; ++j) {
            float v = xr[j] * DT;
            unsigned short hh = f2bf(v);
            h[j] = hh;
            lo[j] = f2bf(v - bf2f(hh));
        }
    }
    *(u16x8*)(Xh + (size_t)m * 64 + u * 8) = h;
    *(u16x8*)(Xl + (size_t)m * 64 + u * 8) = lo;
}

// -------- y0 = X[:,0] @ init_W^T + init_b --------
__global__ __launch_bounds__(256) void k_y0(const float* __restrict__ X,
                                            const float* __restrict__ W,
                                            const float* __restrict__ bias,
                                            float* __restrict__ out) {
    int idx = blockIdx.x * 256 + threadIdx.x;
    int b = idx >> 7, h = idx & 127;
    const float* xr = X + (size_t)b * Sz * Dz;
    const float* wr = W + (size_t)h * Dz;
    float acc = bias[h];
    for (int d = 0; d < Dz; ++d) acc += xr[d] * wr[d];
    out[(size_t)b * Sz * Hz + h] = acc;
}

// -------- Bs[bt,h] --------
__global__ __launch_bounds__(256) void k_bs(const float* __restrict__ X,
                                            const float* __restrict__ WB,
                                            float* __restrict__ Bs) {
    int idx = blockIdx.x * 256 + threadIdx.x;
    int bt = idx >> 7, h = idx & 127;
    int b = bt / NT, t = bt - b * NT;
    const float* xr = X + ((size_t)b * Sz + t + 1) * Dz;
    const float* wr = WB + (size_t)h * KK;
    float acc = wr[0];
    for (int k = 0; k < Dz; ++k) acc += xr[k] * wr[1 + k];
    Bs[(size_t)bt * Hz + h] = acc * DT;
}

// -------- As GEMM via MFMA, 2-term bf16 split (~fp32 accurate) --------
// block 256 thr (4 waves 2x2), tile 128 bt x 128 o, K=64 single pass.
// As[m][o] = bf16( xh*Wh + xh*Wl + xl*Wh + DT*WA[o][0] )
__global__ __launch_bounds__(256) void k_gemm_mfma(
    const unsigned short* __restrict__ Xh, const unsigned short* __restrict__ Xl,
    const unsigned short* __restrict__ Wh, const unsigned short* __restrict__ Wl,
    const float* __restrict__ WA0d, unsigned short* __restrict__ As, int M) {
    const int tid = threadIdx.x;
    const int w = tid >> 6, l = tid & 63;
    const int lr = l & 15, lg = l >> 4;
    const int wbt = w >> 1, wo = w & 1;
    const int o0 = blockIdx.x * 128;
    const int bt0 = blockIdx.y * 128;

    __shared__ __align__(16) unsigned short L[4 * 8192];  // Xh|Xl|Wh|Wl 128x64

    // stage 4 x 16KB via global_load_lds, source pre-swizzled (XOR unit^row&7)
#pragma unroll
    for (int q = 0; q < 4; ++q) {
        int seg = w * 4 + q;                 // 0..15 per buffer
        int du = seg * 64 + l;               // 0..1023
        int row = du >> 3;
        int su = (du & ~7) | ((du & 7) ^ (row & 7));
        dma16(Xh + (size_t)bt0 * 64 + su * 8, &L[0 * 8192 + seg * 512]);
        dma16(Xl + (size_t)bt0 * 64 + su * 8, &L[1 * 8192 + seg * 512]);
        dma16(Wh + (size_t)o0 * 64 + su * 8, &L[2 * 8192 + seg * 512]);
        dma16(Wl + (size_t)o0 * 64 + su * 8, &L[3 * 8192 + seg * 512]);
    }
    __syncthreads();   // implicit vmcnt(0): all staging done

    f32x4 acc[4][4] = {};   // [oti][bti]
    const unsigned short* Xh_l = &L[0];
    const unsigned short* Xl_l = &L[8192];
    const unsigned short* Wh_l = &L[16384];
    const unsigned short* Wl_l = &L[24576];

#pragma unroll
    for (int kk = 0; kk < 2; ++kk) {
        short8 xh[4], xl[4], wh[4], wl[4];
#pragma unroll
        for (int t = 0; t < 4; ++t) {
            int btr = wbt * 64 + t * 16 + lr;
            int orr = wo * 64 + t * 16 + lr;
            int ux = (kk * 4 + lg) ^ (btr & 7);
            int uw = (kk * 4 + lg) ^ (orr & 7);
            xh[t] = *(const short8*)&Xh_l[btr * 64 + ux * 8];
            xl[t] = *(const short8*)&Xl_l[btr * 64 + ux * 8];
            wh[t] = *(const short8*)&Wh_l[orr * 64 + uw * 8];
            wl[t] = *(const short8*)&Wl_l[orr * 64 + uw * 8];
        }
#pragma unroll
        for (int ot = 0; ot < 4; ++ot)
#pragma unroll
            for (int bt = 0; bt < 4; ++bt) {
                acc[ot][bt] = __builtin_amdgcn_mfma_f32_16x16x32_bf16(
                    wh[ot], xh[bt], acc[ot][bt], 0, 0, 0);
                acc[ot][bt] = __builtin_amdgcn_mfma_f32_16x16x32_bf16(
                    wh[ot], xl[bt], acc[ot][bt], 0, 0, 0);
                acc[ot][bt] = __builtin_amdgcn_mfma_f32_16x16x32_bf16(
                    wl[ot], xh[bt], acc[ot][bt], 0, 0, 0);
            }
    }

    __syncthreads();                       // all frag reads done; reuse L[0:16K)
    unsigned short* T = &L[0];             // 128 bt x 128 o bf16, 8B-unit swizzle
#pragma unroll
    for (int ot = 0; ot < 4; ++ot) {
        int obase = wo * 64 + ot * 16 + lg * 4;
        float4 wa = *(const float4*)&WA0d[o0 + obase];
#pragma unroll
        for (int bt = 0; bt < 4; ++bt) {
            int btl = wbt * 64 + bt * 16 + lr;
            u16x4 pk;
            pk[0] = f2bf(acc[ot][bt][0] + wa.x);
            pk[1] = f2bf(acc[ot][bt][1] + wa.y);
            pk[2] = f2bf(acc[ot][bt][2] + wa.z);
            pk[3] = f2bf(acc[ot][bt][3] + wa.w);
            int u8i = (obase >> 2) ^ ((btl & 7) << 1);
            *(u16x4*)&T[btl * 128 + (u8i << 2)] = pk;
        }
    }
    __syncthreads();
    // stream T -> As (row-coalesced)
    int row = tid >> 1, half = tid & 1;
    int btv = bt0 + row;
    if (btv < M) {
#pragma unroll
        for (int j = 0; j < 8; ++j) {
            int u = half * 16 + j * 2;
            int up = u ^ ((row & 7) << 1);   // even XOR keeps pair adjacent
            u16x8 val = *(const u16x8*)&T[row * 128 + (up << 2)];
            *(u16x8*)(As + (size_t)btv * OO + o0 + half * 64 + j * 8) = val;
        }
    }
}

// -------- stage helper for chunk_a --------
__device__ __forceinline__ void stage_a(const unsigned short* Ab, int step,
                                        unsigned short* AbufF, int buf,
                                        int w, int l) {
    const unsigned short* src = Ab + (size_t)step * OO;
#pragma unroll
    for (int q = 0; q < 2; ++q) {
        int seg = w * 2 + q;                 // 0..31
        int du = seg * 64 + l;               // 0..2047
        int row = du >> 4, cu = du & 15;
        int su = (du & ~15) | (cu ^ (row & 7));
        dma16(src + (size_t)su * 8, &AbufF[buf * OO + seg * 512]);
    }
}

// -------- stage a: per-chunk Delta (128x128) and v via MFMA --------
// 1024 thr = 16 waves (4x4). Ring-3 A staging (global_load_lds), counted
// vmcnt(2), raw s_barrier. Bs chunk in LDS. Wave (wr,wc): 2x2 Delta tiles;
// waves 0..7 additionally own v segment w.
__global__ __launch_bounds__(1024) void k_chunk_a(
    const unsigned short* __restrict__ As, const float* __restrict__ Bs,
    float* __restrict__ Dm, float* __restrict__ Vv,
    int t0, int Lsteps, int NCs) {
    const int cs = blockIdx.x, b = blockIdx.y;
    const int tid = threadIdx.x;
    const int w = tid >> 6, l = tid & 63;
    const int lr = l & 15, lg = l >> 4;
    const int wr = w >> 2, wc = w & 3;
    int Lc = Lsteps - cs * CHUNK; if (Lc > CHUNK) Lc = CHUNK;

    __shared__ __align__(16) unsigned short AbufF[3 * OO];   // 96 KB ring
    __shared__ __align__(16) unsigned short Pt[129 * Hz];    // 33 KB (P^T ; v)
    __shared__ __align__(16) float BsL[CHUNK][Hz];           // 8 KB

    // Pt = [I ; v=0] (swizzled rows)
    for (int idx = tid; idx < 129 * Hz; idx += 1024) {
        int row = idx >> 7, col = idx & 127;
        unsigned short val = (row < Hz && row == col) ? (unsigned short)0x3F80
                                                      : (unsigned short)0;
        int unit = (col >> 3) ^ (row & 7);
        Pt[(row << 7) | (unit << 3) | (col & 7)] = val;
    }
    // Bs chunk -> LDS (removes per-step vmem load from the loop)
    const int t0c = t0 + cs * CHUNK;
    for (int idx = tid; idx < Lc * Hz; idx += 1024) {
        int row = idx >> 7, col = idx & 127;
        BsL[row][col] = Bs[((size_t)b * NT + t0c + row) * Hz + col];
    }

    const unsigned short* Ab = As + ((size_t)b * Lsteps + cs * CHUNK) * OO;

    // identity addend (precomputed, no per-step cndmask)
    float idv[2][2][4];
#pragma unroll
    for (int tix = 0; tix < 2; ++tix)
#pragma unroll
        for (int tjx = 0; tjx < 2; ++tjx) {
            int i0 = 32 * wr + 16 * tix + 4 * lg;
            int j = 32 * wc + 16 * tjx + lr;
#pragma unroll
            for (int r = 0; r < 4; ++r)
                idv[tix][tjx][r] = (i0 + r == j) ? 1.f : 0.f;
        }

    stage_a(Ab, 0, AbufF, 0, w, l);
    if (Lc > 1) stage_a(Ab, 1, AbufF, 1, w, l);

    f32x4 acc[2][2] = {};
    f32x4 vacc = {};
    int b0 = 0, b1 = 1, b2 = 2;
    const int kxor = lr & 7;

    for (int k = 0; k < Lc; ++k) {
        // barrier #1: buf[b0] DMA (issued at k-2) done; k+1's stays in flight
        if (k + 1 < Lc) {
            asm volatile("s_waitcnt vmcnt(2) lgkmcnt(0)" ::: "memory");
        } else {
            asm volatile("s_waitcnt vmcnt(0) lgkmcnt(0)" ::: "memory");
        }
        __builtin_amdgcn_s_barrier();
        asm volatile("" ::: "memory");

        if (k + 2 < Lc) stage_a(Ab, k + 2, AbufF, b2, w, l);

        const unsigned short* Ac = &AbufF[b0 * OO];
#pragma unroll
        for (int kt = 0; kt < 4; ++kt) {
            const int uoff = ((kt * 4 + lg) ^ kxor) << 3;
            short8 af0 = *(const short8*)&Ac[((32 * wr + lr) << 7) | uoff];
            short8 af1 = *(const short8*)&Ac[((32 * wr + 16 + lr) << 7) | uoff];
            short8 bf0 = *(const short8*)&Pt[((32 * wc + lr) << 7) | uoff];
            short8 bf1 = *(const short8*)&Pt[((32 * wc + 16 + lr) << 7) | uoff];
            acc[0][0] = __builtin_amdgcn_mfma_f32_16x16x32_bf16(af0, bf0,
                                                                acc[0][0], 0, 0, 0);
            acc[0][1] = __builtin_amdgcn_mfma_f32_16x16x32_bf16(af0, bf1,
                                                                acc[0][1], 0, 0, 0);
            acc[1][0] = __builtin_amdgcn_mfma_f32_16x16x32_bf16(af1, bf0,
                                                                acc[1][0], 0, 0, 0);
            acc[1][1] = __builtin_amdgcn_mfma_f32_16x16x32_bf16(af1, bf1,
                                                                acc[1][1], 0, 0, 0);
            if (w < 8) {
                short8 afv = *(const short8*)&Ac[((16 * w + lr) << 7) | uoff];
                short8 vf = *(const short8*)&Pt[(128 << 7) | ((kt * 4 + lg) << 3)];
                vacc = __builtin_amdgcn_mfma_f32_16x16x32_bf16(afv, vf, vacc,
                                                               0, 0, 0);
            }
        }

        // barrier #2: all Pt reads done before rewrite
        asm volatile("s_waitcnt lgkmcnt(0)" ::: "memory");
        __builtin_amdgcn_s_barrier();
        asm volatile("" ::: "memory");

        // Pt := (I + Delta)^T
#pragma unroll
        for (int tix = 0; tix < 2; ++tix)
#pragma unroll
            for (int tjx = 0; tjx < 2; ++tjx) {
                int i0 = 32 * wr + 16 * tix + 4 * lg;
                int j = 32 * wc + 16 * tjx + lr;
                u16x4 pk;
#pragma unroll
                for (int r = 0; r < 4; ++r)
                    pk[r] = f2bf(acc[tix][tjx][r] + idv[tix][tjx][r]);
                int unit = (i0 >> 3) ^ (j & 7);
                *(u16x4*)&Pt[(j << 7) | (unit << 3) | (i0 & 7)] = pk;
            }
        if (w < 8 && lr == 0) {
            int i0 = 16 * w + 4 * lg;
            const float* bp = &BsL[k][i0];
            u16x4 pk;
#pragma unroll
            for (int r = 0; r < 4; ++r) {
                vacc[r] += bp[r];           // v_k = v + A v + b
                pk[r] = f2bf(vacc[r]);
            }
            *(u16x4*)&Pt[(128 << 7) | ((i0 >> 3) << 3) | (i0 & 7)] = pk;
        }
        int tmp = b0; b0 = b1; b1 = b2; b2 = tmp;
    }

    // write Delta (fp32) + v
    const size_t ci = (size_t)b * NCs + cs;
    float* D = Dm + ci * OO;
#pragma unroll
    for (int tix = 0; tix < 2; ++tix)
#pragma unroll
        for (int tjx = 0; tjx < 2; ++tjx) {
            int i0 = 32 * wr + 16 * tix + 4 * lg;
            int j = 32 * wc + 16 * tjx + lr;
#pragma unroll
            for (int r = 0; r < 4; ++r)
                D[(size_t)(i0 + r) * Hz + j] = acc[tix][tjx][r];
        }
    if (w < 8 && lr == 0) {
        int i0 = 16 * w + 4 * lg;
        float* V = Vv + ci * Hz;
#pragma unroll
        for (int r = 0; r < 4; ++r) V[i0 + r] = vacc[r];
    }
}

// -------- stage b: sequential over chunks, y_end = y + Delta y + v --------
__global__ __launch_bounds__(512) void k_chunk_b(
    const float* __restrict__ Dm, const float* __restrict__ Vv,
    float* __restrict__ out, int t0, int Lsteps, int NCs) {
    const int b = blockIdx.x, tid = threadIdx.x;
    const int q = tid >> 7, i = tid & 127;
    __shared__ float yv[Hz];
    __shared__ float part[4][Hz];
    __shared__ float VvL[32 * Hz];

    if (tid < Hz) yv[tid] = out[((size_t)b * Sz + t0) * Hz + tid];
    for (int idx = tid; idx < NCs * Hz; idx += 512)
        VvL[idx] = Vv[(size_t)b * NCs * Hz + idx];
    __syncthreads();

    const float4* D0 = (const float4*)(Dm + (size_t)b * NCs * OO);
    const int off = i * 32 + q * 8;        // float4 index: row i, cols q*32..
    float4 cur[8];
#pragma unroll
    for (int v = 0; v < 8; ++v) cur[v] = D0[off + v];

    for (int cs = 0; cs < NCs; ++cs) {
        float4 nxt[8];
        int nc = (cs + 1 < NCs) ? cs + 1 : cs;
        const float4* Dn = D0 + (size_t)nc * (OO / 4);
#pragma unroll
        for (int v = 0; v < 8; ++v) nxt[v] = Dn[off + v];   // in flight

        float s = 0.f;
#pragma unroll
        for (int v = 0; v < 8; ++v) {
            const float* yp = &yv[q * 32 + v * 4];
            s += cur[v].x * yp[0] + cur[v].y * yp[1] + cur[v].z * yp[2] +
                 cur[v].w * yp[3];
        }
        part[q][i] = s;
        __syncthreads();
        if (tid < Hz) {
            float yn = yv[tid] + part[0][tid] + part[1][tid] + part[2][tid] +
                       part[3][tid] + VvL[cs * Hz + tid];
            yv[tid] = yn;
            int t_end = t0 + (cs + 1) * CHUNK;
            if (t_end < Sz)
                out[((size_t)b * Sz + t_end) * Hz + tid] = yn;  // boundary row
        }
        __syncthreads();
#pragma unroll
        for (int v = 0; v < 8; ++v) cur[v] = nxt[v];
    }
}

// -------- stage c: 16-step replay per chunk (interior rows) --------
__global__ __launch_bounds__(1024) void k_chunk_c(
    const unsigned short* __restrict__ As, const float* __restrict__ Bs,
    float* __restrict__ out, int t0, int Lsteps, int NCs) {
    const int cs = blockIdx.x, b = blockIdx.y;
    const int tid = threadIdx.x;
    const int i = tid >> 3, p = tid & 7;
    const int t0c = t0 + cs * CHUNK;
    int Lc = Lsteps - cs * CHUNK; if (Lc > CHUNK) Lc = CHUNK;
    __shared__ __align__(16) float y[2][Hz];

    if (tid < Hz) y[0][tid] = out[((size_t)b * Sz + t0c) * Hz + tid];
    __syncthreads();

    const unsigned short* Abp =
        As + ((size_t)b * Lsteps + cs * CHUNK) * OO + i * Hz + p * 16;
    const float* Bsb = Bs + (size_t)b * NT * Hz;
    float* outb = out + (size_t)b * Sz * Hz;

    u16x8 c0 = *(const u16x8*)(Abp);
    u16x8 c1 = *(const u16x8*)(Abp + 8);
    int l1 = (Lc > 1) ? 1 : 0;
    u16x8 d0 = *(const u16x8*)(Abp + (size_t)l1 * OO);
    u16x8 d1 = *(const u16x8*)(Abp + (size_t)l1 * OO + 8);

    for (int lt = 0; lt < Lc; ++lt) {
        int ln = lt + 2; if (ln > Lc - 1) ln = Lc - 1;
        u16x8 e0 = *(const u16x8*)(Abp + (size_t)ln * OO);
        u16x8 e1 = *(const u16x8*)(Abp + (size_t)ln * OO + 8);

        const int cur = lt & 1;
        const float4* yp = (const float4*)&y[cur][p * 16];
        float4 y0v = yp[0], y1v = yp[1], y2v = yp[2], y3v = yp[3];

        float s;
        s  = bf2f(c0[0]) * y0v.x + bf2f(c0[1]) * y0v.y +
             bf2f(c0[2]) * y0v.z + bf2f(c0[3]) * y0v.w;
        s += bf2f(c0[4]) * y1v.x + bf2f(c0[5]) * y1v.y +
             bf2f(c0[6]) * y1v.z + bf2f(c0[7]) * y1v.w;
        s += bf2f(c1[0]) * y2v.x + bf2f(c1[1]) * y2v.y +
             bf2f(c1[2]) * y2v.z + bf2f(c1[3]) * y2v.w;
        s += bf2f(c1[4]) * y3v.x + bf2f(c1[5]) * y3v.y +
             bf2f(c1[6]) * y3v.z + bf2f(c1[7]) * y3v.w;
        s += __shfl_xor(s, 1);
        s += __shfl_xor(s, 2);
        s += __shfl_xor(s, 4);

        if (p == 0) {
            int t = t0c + lt;
            float st = s + Bsb[(size_t)t * Hz + i];
            float yn = y[cur][i] + st;
            y[cur ^ 1][i] = yn;
            if (((t + 1) & (CHUNK - 1)) != 0)        // boundaries: stage b
                outb[(size_t)(t + 1) * Hz + i] = yn;
        }
        c0 = d0; c1 = d1; d0 = e0; d1 = e1;
        __syncthreads();
    }
}

// -------- fallback (ws tiny) --------
__global__ __launch_bounds__(1024) void k_fused(const float* __restrict__ X,
                                                const float* __restrict__ initW,
                                                const float* __restrict__ initb,
                                                const float* __restrict__ WA,
                                                const float* __restrict__ WB,
                                                float* __restrict__ out) {
    const int b = blockIdx.x, tid = threadIdx.x;
    const int i = tid >> 3, p = tid & 7;
    __shared__ float y[2][Hz];
    __shared__ float u[KK];

    if (tid < Hz) {
        float a = initb[tid];
        const float* xr = X + (size_t)b * Sz * Dz;
        const float* wr = initW + (size_t)tid * Dz;
        for (int d = 0; d < Dz; ++d) a += xr[d] * wr[d];
        y[0][tid] = a;
        out[(size_t)b * Sz * Hz + tid] = a;
    }
    __syncthreads();

    for (int t = 0; t < NT; ++t) {
        if (tid < KK)
            u[tid] = (tid == 0) ? DT
                                : X[((size_t)b * Sz + t + 1) * Dz + tid - 1] * DT;
        __syncthreads();
        const int cur = t & 1;
        float partial = 0.f;
        for (int jj = 0; jj < 16; ++jj) {
            int j = p * 16 + jj;
            const float* wr = WA + (size_t)(i * Hz + j) * KK;
            float a = 0.f;
            for (int d = 0; d < KK; ++d) a += wr[d] * u[d];
            partial += a * y[cur][j];
        }
        partial += __shfl_xor(partial, 1);
        partial += __shfl_xor(partial, 2);
        partial += __shfl_xor(partial, 4);
        if (p == 0) {
            const float* wb = WB + (size_t)i * KK;
            float bv = 0.f;
            for (int d = 0; d < KK; ++d) bv += wb[d] * u[d];
            float yn = y[cur][i] + partial + bv;
            y[cur ^ 1][i] = yn;
            out[(size_t)b * Sz * Hz + (size_t)(t + 1) * Hz + i] = yn;
        }
        __syncthreads();
    }
}

extern "C" void kernel_launch(void* const* d_in, const int* in_sizes, int n_in,
                              void* d_out, int out_size, void* d_ws,
                              size_t ws_size, hipStream_t stream) {
    const float* X = (const float*)d_in[0];
    const float* initW = (const float*)d_in[1];
    const float* initb = (const float*)d_in[2];
    const float* WA = (const float*)d_in[3];
    const float* WB = (const float*)d_in[4];
    float* out = (float*)d_out;

    // ws layout
    const size_t WH_OFF = 0;                          // 2 MB
    const size_t WL_OFF = 2097152;                    // 2 MB
    const size_t WA0_OFF = 4194304;                   // 64 KB
    const size_t XH_OFF = 4259840;                    // 512 KB (4096 x 64)
    const size_t XL_OFF = 4784128;                    // 512 KB
    const size_t BS_OFF = 5308416;                    // 2 MB (8*511*128 f32)
    const size_t base = 7401472;
    const size_t PER_SC = (size_t)Bz * OO * 4 +       // Dm per chunk-col
                          (size_t)Bz * Hz * 4 +       // Vv per chunk-col
                          (size_t)Bz * CHUNK * OO * 2;// As per chunk-col
    const int NC = (NT + CHUNK - 1) / CHUNK;          // 32

    long SC_max = (ws_size > base) ? (long)((ws_size - base) / PER_SC) : 0;
    if (SC_max >= 1) {
        if (SC_max > NC) SC_max = NC;
        int nS = (NC + (int)SC_max - 1) / (int)SC_max;
        int SC = (NC + nS - 1) / nS;

        unsigned short* Wh = (unsigned short*)((char*)d_ws + WH_OFF);
        unsigned short* Wl = (unsigned short*)((char*)d_ws + WL_OFF);
        float* WA0d = (float*)((char*)d_ws + WA0_OFF);
        unsigned short* Xh = (unsigned short*)((char*)d_ws + XH_OFF);
        unsigned short* Xl = (unsigned short*)((char*)d_ws + XL_OFF);
        float* Bs = (float*)((char*)d_ws + BS_OFF);
        float* Dm = (float*)((char*)d_ws + base);
        float* Vv = (float*)((char*)d_ws + base + (size_t)SC * Bz * OO * 4);
        unsigned short* As = (unsigned short*)((char*)d_ws + base +
                                               (size_t)SC * Bz * OO * 4 +
                                               (size_t)SC * Bz * Hz * 4);

        k_wsplit<<<512, 256, 0, stream>>>(WA, Wh, Wl, WA0d);
        k_y0<<<4, 256, 0, stream>>>(X, initW, initb, out);
        k_bs<<<2044, 256, 0, stream>>>(X, WB, Bs);

        for (int c0 = 0; c0 < NC; c0 += SC) {
            int t0 = c0 * CHUNK;
            int Lsteps = NT - t0;
            if (Lsteps > SC * CHUNK) Lsteps = SC * CHUNK;
            int NCs = (Lsteps + CHUNK - 1) / CHUNK;
            int M = Bz * Lsteps;
            int Mpad = (M + 127) & ~127;
            k_prep<<<128, 256, 0, stream>>>(X, Xh, Xl, t0, Lsteps);
            k_gemm_mfma<<<dim3(128, Mpad / 128), 256, 0, stream>>>(
                Xh, Xl, Wh, Wl, WA0d, As, M);
            k_chunk_a<<<dim3(NCs, Bz), 1024, 0, stream>>>(As, Bs, Dm, Vv, t0,
                                                          Lsteps, NCs);
            k_chunk_b<<<Bz, 512, 0, stream>>>(Dm, Vv, out, t0, Lsteps, NCs);
            k_chunk_c<<<dim3(NCs, Bz), 1024, 0, stream>>>(As, Bs, out, t0,
                                                          Lsteps, NCs);
        }
    } else {
        k_fused<<<Bz, 1024, 0, stream>>>(X, initW, initb, WA, WB, out);
    }
}

// Round 5
// 204.088 us; speedup vs baseline: 283.7277x; 1.1929x over previous
//
#include <hip/hip_runtime.h>
#include <hip/hip_bf16.h>

// LinearCDE: y_{t+1} = y_t + A_t y_t + b_t, A_t = reshape(vf_A_W @ u_t, HxH),
// u_t = [1, X[:,t+1]] * DT.  CLIP=1e11 => tanh is identity to ~1e-10 rel.
//
// Round-4 changes: (1) k_chunk_b: shfl-reduce + yv double-buffer => single
// raw s_barrier/iter (lgkmcnt only, no vmcnt drain), depth-2 register
// prefetch of Delta tiles. (2) k_chunk_c: raw s_barrier per step so the
// depth-2 A prefetch actually stays in flight (old __syncthreads drained it).
#define DT 0.025f
#define Bz 8
#define Sz 512
#define Dz 64
#define Hz 128
#define NT 511            // S-1 steps
#define OO (Hz * Hz)      // 16384
#define KK (Dz + 1)       // 65
#define CHUNK 16

using short8 = __attribute__((ext_vector_type(8))) short;
using f32x4  = __attribute__((ext_vector_type(4))) float;
using u16x8  = __attribute__((ext_vector_type(8))) unsigned short;
using u16x4  = __attribute__((ext_vector_type(4))) unsigned short;

__device__ __forceinline__ float bf2f(unsigned short u) {
    union { unsigned int i; float f; } v;
    v.i = ((unsigned int)u) << 16;
    return v.f;
}
__device__ __forceinline__ unsigned short f2bf(float f) {
    union { float f; unsigned int i; } v;
    v.f = f;
    unsigned int u = v.i;
    return (unsigned short)((u + 0x7FFFu + ((u >> 16) & 1u)) >> 16);  // RNE
}

// async 16B global -> LDS (dest: wave-uniform base + lane*16)
__device__ __forceinline__ void dma16(const void* g, void* s) {
    __builtin_amdgcn_global_load_lds(
        (const __attribute__((address_space(1))) unsigned int*)g,
        (__attribute__((address_space(3))) unsigned int*)s, 16, 0, 0);
}

// -------- split vf_A_W: Wh/Wl bf16 [o][64] (d=1..64), WA0d = DT*col0 --------
__global__ __launch_bounds__(256) void k_wsplit(const float* __restrict__ WA,
                                                unsigned short* __restrict__ Wh,
                                                unsigned short* __restrict__ Wl,
                                                float* __restrict__ WA0d) {
    int idx = blockIdx.x * 256 + threadIdx.x;   // 512 blocks: 16384 o x 8 units
    int o = idx >> 3, u = idx & 7;
    const float* wr = WA + (size_t)o * KK + 1 + u * 8;
    u16x8 h = {}, lo = {};
#pragma unroll
    for (int j = 0; j < 8; ++j) {
        float v = wr[j];
        unsigned short hh = f2bf(v);
        h[j] = hh;
        lo[j] = f2bf(v - bf2f(hh));
    }
    *(u16x8*)(Wh + (size_t)o * 64 + u * 8) = h;
    *(u16x8*)(Wl + (size_t)o * 64 + u * 8) = lo;
    if (u == 0) WA0d[o] = DT * WA[(size_t)o * KK];
}

// -------- per-slice u split: Xh/Xl bf16 [m][64], m = b*Lsteps+lt, pad 0 -----
__global__ __launch_bounds__(256) void k_prep(const float* __restrict__ X,
                                              unsigned short* __restrict__ Xh,
                                              unsigned short* __restrict__ Xl,
                                              int t0, int Lsteps) {
    int idx = blockIdx.x * 256 + threadIdx.x;   // 128 blocks: 4096 m x 8 units
    int m = idx >> 3, u = idx & 7;
    int Mr = Bz * Lsteps;
    u16x8 h = {}, lo = {};
    if (m < Mr) {
        int b = m / Lsteps, lt = m - b * Lsteps;
        const float* xr = X + ((size_t)b * Sz + t0 + lt + 1) * Dz + u * 8;
#pragma unroll
        for (int j = 0; j < 8; ++j) {
            float v = xr[j] * DT;
            unsigned short hh = f2bf(v);
            h[j] = hh;
            lo[j] = f2bf(v - bf2f(hh));
        }
    }
    *(u16x8*)(Xh + (size_t)m * 64 + u * 8) = h;
    *(u16x8*)(Xl + (size_t)m * 64 + u * 8) = lo;
}

// -------- y0 = X[:,0] @ init_W^T + init_b --------
__global__ __launch_bounds__(256) void k_y0(const float* __restrict__ X,
                                            const float* __restrict__ W,
                                            const float* __restrict__ bias,
                                            float* __restrict__ out) {
    int idx = blockIdx.x * 256 + threadIdx.x;
    int b = idx >> 7, h = idx & 127;
    const float* xr = X + (size_t)b * Sz * Dz;
    const float* wr = W + (size_t)h * Dz;
    float acc = bias[h];
    for (int d = 0; d < Dz; ++d) acc += xr[d] * wr[d];
    out[(size_t)b * Sz * Hz + h] = acc;
}

// -------- Bs[bt,h] --------
__global__ __launch_bounds__(256) void k_bs(const float* __restrict__ X,
                                            const float* __restrict__ WB,
                                            float* __restrict__ Bs) {
    int idx = blockIdx.x * 256 + threadIdx.x;
    int bt = idx >> 7, h = idx & 127;
    int b = bt / NT, t = bt - b * NT;
    const float* xr = X + ((size_t)b * Sz + t + 1) * Dz;
    const float* wr = WB + (size_t)h * KK;
    float acc = wr[0];
    for (int k = 0; k < Dz; ++k) acc += xr[k] * wr[1 + k];
    Bs[(size_t)bt * Hz + h] = acc * DT;
}

// -------- As GEMM via MFMA, 2-term bf16 split (~fp32 accurate) --------
__global__ __launch_bounds__(256) void k_gemm_mfma(
    const unsigned short* __restrict__ Xh, const unsigned short* __restrict__ Xl,
    const unsigned short* __restrict__ Wh, const unsigned short* __restrict__ Wl,
    const float* __restrict__ WA0d, unsigned short* __restrict__ As, int M) {
    const int tid = threadIdx.x;
    const int w = tid >> 6, l = tid & 63;
    const int lr = l & 15, lg = l >> 4;
    const int wbt = w >> 1, wo = w & 1;
    const int o0 = blockIdx.x * 128;
    const int bt0 = blockIdx.y * 128;

    __shared__ __align__(16) unsigned short L[4 * 8192];  // Xh|Xl|Wh|Wl 128x64

#pragma unroll
    for (int q = 0; q < 4; ++q) {
        int seg = w * 4 + q;                 // 0..15 per buffer
        int du = seg * 64 + l;               // 0..1023
        int row = du >> 3;
        int su = (du & ~7) | ((du & 7) ^ (row & 7));
        dma16(Xh + (size_t)bt0 * 64 + su * 8, &L[0 * 8192 + seg * 512]);
        dma16(Xl + (size_t)bt0 * 64 + su * 8, &L[1 * 8192 + seg * 512]);
        dma16(Wh + (size_t)o0 * 64 + su * 8, &L[2 * 8192 + seg * 512]);
        dma16(Wl + (size_t)o0 * 64 + su * 8, &L[3 * 8192 + seg * 512]);
    }
    __syncthreads();   // implicit vmcnt(0): all staging done

    f32x4 acc[4][4] = {};   // [oti][bti]
    const unsigned short* Xh_l = &L[0];
    const unsigned short* Xl_l = &L[8192];
    const unsigned short* Wh_l = &L[16384];
    const unsigned short* Wl_l = &L[24576];

#pragma unroll
    for (int kk = 0; kk < 2; ++kk) {
        short8 xh[4], xl[4], wh[4], wl[4];
#pragma unroll
        for (int t = 0; t < 4; ++t) {
            int btr = wbt * 64 + t * 16 + lr;
            int orr = wo * 64 + t * 16 + lr;
            int ux = (kk * 4 + lg) ^ (btr & 7);
            int uw = (kk * 4 + lg) ^ (orr & 7);
            xh[t] = *(const short8*)&Xh_l[btr * 64 + ux * 8];
            xl[t] = *(const short8*)&Xl_l[btr * 64 + ux * 8];
            wh[t] = *(const short8*)&Wh_l[orr * 64 + uw * 8];
            wl[t] = *(const short8*)&Wl_l[orr * 64 + uw * 8];
        }
#pragma unroll
        for (int ot = 0; ot < 4; ++ot)
#pragma unroll
            for (int bt = 0; bt < 4; ++bt) {
                acc[ot][bt] = __builtin_amdgcn_mfma_f32_16x16x32_bf16(
                    wh[ot], xh[bt], acc[ot][bt], 0, 0, 0);
                acc[ot][bt] = __builtin_amdgcn_mfma_f32_16x16x32_bf16(
                    wh[ot], xl[bt], acc[ot][bt], 0, 0, 0);
                acc[ot][bt] = __builtin_amdgcn_mfma_f32_16x16x32_bf16(
                    wl[ot], xh[bt], acc[ot][bt], 0, 0, 0);
            }
    }

    __syncthreads();                       // all frag reads done; reuse L[0:16K)
    unsigned short* T = &L[0];             // 128 bt x 128 o bf16, 8B-unit swizzle
#pragma unroll
    for (int ot = 0; ot < 4; ++ot) {
        int obase = wo * 64 + ot * 16 + lg * 4;
        float4 wa = *(const float4*)&WA0d[o0 + obase];
#pragma unroll
        for (int bt = 0; bt < 4; ++bt) {
            int btl = wbt * 64 + bt * 16 + lr;
            u16x4 pk;
            pk[0] = f2bf(acc[ot][bt][0] + wa.x);
            pk[1] = f2bf(acc[ot][bt][1] + wa.y);
            pk[2] = f2bf(acc[ot][bt][2] + wa.z);
            pk[3] = f2bf(acc[ot][bt][3] + wa.w);
            int u8i = (obase >> 2) ^ ((btl & 7) << 1);
            *(u16x4*)&T[btl * 128 + (u8i << 2)] = pk;
        }
    }
    __syncthreads();
    int row = tid >> 1, half = tid & 1;
    int btv = bt0 + row;
    if (btv < M) {
#pragma unroll
        for (int j = 0; j < 8; ++j) {
            int u = half * 16 + j * 2;
            int up = u ^ ((row & 7) << 1);   // even XOR keeps pair adjacent
            u16x8 val = *(const u16x8*)&T[row * 128 + (up << 2)];
            *(u16x8*)(As + (size_t)btv * OO + o0 + half * 64 + j * 8) = val;
        }
    }
}

// -------- stage helper for chunk_a --------
__device__ __forceinline__ void stage_a(const unsigned short* Ab, int step,
                                        unsigned short* AbufF, int buf,
                                        int w, int l) {
    const unsigned short* src = Ab + (size_t)step * OO;
#pragma unroll
    for (int q = 0; q < 2; ++q) {
        int seg = w * 2 + q;                 // 0..31
        int du = seg * 64 + l;               // 0..2047
        int row = du >> 4, cu = du & 15;
        int su = (du & ~15) | (cu ^ (row & 7));
        dma16(src + (size_t)su * 8, &AbufF[buf * OO + seg * 512]);
    }
}

// -------- stage a: per-chunk Delta (128x128) and v via MFMA --------
__global__ __launch_bounds__(1024) void k_chunk_a(
    const unsigned short* __restrict__ As, const float* __restrict__ Bs,
    float* __restrict__ Dm, float* __restrict__ Vv,
    int t0, int Lsteps, int NCs) {
    const int cs = blockIdx.x, b = blockIdx.y;
    const int tid = threadIdx.x;
    const int w = tid >> 6, l = tid & 63;
    const int lr = l & 15, lg = l >> 4;
    const int wr = w >> 2, wc = w & 3;
    int Lc = Lsteps - cs * CHUNK; if (Lc > CHUNK) Lc = CHUNK;

    __shared__ __align__(16) unsigned short AbufF[3 * OO];   // 96 KB ring
    __shared__ __align__(16) unsigned short Pt[129 * Hz];    // 33 KB (P^T ; v)
    __shared__ __align__(16) float BsL[CHUNK][Hz];           // 8 KB

    for (int idx = tid; idx < 129 * Hz; idx += 1024) {
        int row = idx >> 7, col = idx & 127;
        unsigned short val = (row < Hz && row == col) ? (unsigned short)0x3F80
                                                      : (unsigned short)0;
        int unit = (col >> 3) ^ (row & 7);
        Pt[(row << 7) | (unit << 3) | (col & 7)] = val;
    }
    const int t0c = t0 + cs * CHUNK;
    for (int idx = tid; idx < Lc * Hz; idx += 1024) {
        int row = idx >> 7, col = idx & 127;
        BsL[row][col] = Bs[((size_t)b * NT + t0c + row) * Hz + col];
    }

    const unsigned short* Ab = As + ((size_t)b * Lsteps + cs * CHUNK) * OO;

    float idv[2][2][4];
#pragma unroll
    for (int tix = 0; tix < 2; ++tix)
#pragma unroll
        for (int tjx = 0; tjx < 2; ++tjx) {
            int i0 = 32 * wr + 16 * tix + 4 * lg;
            int j = 32 * wc + 16 * tjx + lr;
#pragma unroll
            for (int r = 0; r < 4; ++r)
                idv[tix][tjx][r] = (i0 + r == j) ? 1.f : 0.f;
        }

    stage_a(Ab, 0, AbufF, 0, w, l);
    if (Lc > 1) stage_a(Ab, 1, AbufF, 1, w, l);

    f32x4 acc[2][2] = {};
    f32x4 vacc = {};
    int b0 = 0, b1 = 1, b2 = 2;
    const int kxor = lr & 7;

    for (int k = 0; k < Lc; ++k) {
        if (k + 1 < Lc) {
            asm volatile("s_waitcnt vmcnt(2) lgkmcnt(0)" ::: "memory");
        } else {
            asm volatile("s_waitcnt vmcnt(0) lgkmcnt(0)" ::: "memory");
        }
        __builtin_amdgcn_s_barrier();
        asm volatile("" ::: "memory");

        if (k + 2 < Lc) stage_a(Ab, k + 2, AbufF, b2, w, l);

        const unsigned short* Ac = &AbufF[b0 * OO];
#pragma unroll
        for (int kt = 0; kt < 4; ++kt) {
            const int uoff = ((kt * 4 + lg) ^ kxor) << 3;
            short8 af0 = *(const short8*)&Ac[((32 * wr + lr) << 7) | uoff];
            short8 af1 = *(const short8*)&Ac[((32 * wr + 16 + lr) << 7) | uoff];
            short8 bf0 = *(const short8*)&Pt[((32 * wc + lr) << 7) | uoff];
            short8 bf1 = *(const short8*)&Pt[((32 * wc + 16 + lr) << 7) | uoff];
            acc[0][0] = __builtin_amdgcn_mfma_f32_16x16x32_bf16(af0, bf0,
                                                                acc[0][0], 0, 0, 0);
            acc[0][1] = __builtin_amdgcn_mfma_f32_16x16x32_bf16(af0, bf1,
                                                                acc[0][1], 0, 0, 0);
            acc[1][0] = __builtin_amdgcn_mfma_f32_16x16x32_bf16(af1, bf0,
                                                                acc[1][0], 0, 0, 0);
            acc[1][1] = __builtin_amdgcn_mfma_f32_16x16x32_bf16(af1, bf1,
                                                                acc[1][1], 0, 0, 0);
            if (w < 8) {
                short8 afv = *(const short8*)&Ac[((16 * w + lr) << 7) | uoff];
                short8 vf = *(const short8*)&Pt[(128 << 7) | ((kt * 4 + lg) << 3)];
                vacc = __builtin_amdgcn_mfma_f32_16x16x32_bf16(afv, vf, vacc,
                                                               0, 0, 0);
            }
        }

        asm volatile("s_waitcnt lgkmcnt(0)" ::: "memory");
        __builtin_amdgcn_s_barrier();
        asm volatile("" ::: "memory");

#pragma unroll
        for (int tix = 0; tix < 2; ++tix)
#pragma unroll
            for (int tjx = 0; tjx < 2; ++tjx) {
                int i0 = 32 * wr + 16 * tix + 4 * lg;
                int j = 32 * wc + 16 * tjx + lr;
                u16x4 pk;
#pragma unroll
                for (int r = 0; r < 4; ++r)
                    pk[r] = f2bf(acc[tix][tjx][r] + idv[tix][tjx][r]);
                int unit = (i0 >> 3) ^ (j & 7);
                *(u16x4*)&Pt[(j << 7) | (unit << 3) | (i0 & 7)] = pk;
            }
        if (w < 8 && lr == 0) {
            int i0 = 16 * w + 4 * lg;
            const float* bp = &BsL[k][i0];
            u16x4 pk;
#pragma unroll
            for (int r = 0; r < 4; ++r) {
                vacc[r] += bp[r];           // v_k = v + A v + b
                pk[r] = f2bf(vacc[r]);
            }
            *(u16x4*)&Pt[(128 << 7) | ((i0 >> 3) << 3) | (i0 & 7)] = pk;
        }
        int tmp = b0; b0 = b1; b1 = b2; b2 = tmp;
    }

    const size_t ci = (size_t)b * NCs + cs;
    float* D = Dm + ci * OO;
#pragma unroll
    for (int tix = 0; tix < 2; ++tix)
#pragma unroll
        for (int tjx = 0; tjx < 2; ++tjx) {
            int i0 = 32 * wr + 16 * tix + 4 * lg;
            int j = 32 * wc + 16 * tjx + lr;
#pragma unroll
            for (int r = 0; r < 4; ++r)
                D[(size_t)(i0 + r) * Hz + j] = acc[tix][tjx][r];
        }
    if (w < 8 && lr == 0) {
        int i0 = 16 * w + 4 * lg;
        float* V = Vv + ci * Hz;
#pragma unroll
        for (int r = 0; r < 4; ++r) V[i0 + r] = vacc[r];
    }
}

// -------- stage b: sequential over chunks, y_end = y + Delta y + v --------
// 1024 thr: row i = tid>>3, col-chunk q = tid&7 (cols q*16..+15).
// shfl-reduce (owners are consecutive lanes), yv double-buffered =>
// one raw s_barrier per iter (lgkmcnt only); depth-2 register prefetch.
__global__ __launch_bounds__(1024) void k_chunk_b(
    const float* __restrict__ Dm, const float* __restrict__ Vv,
    float* __restrict__ out, int t0, int Lsteps, int NCs) {
    const int b = blockIdx.x, tid = threadIdx.x;
    const int i = tid >> 3, q = tid & 7;
    __shared__ __align__(16) float yv[2][Hz];
    __shared__ float VvL[32 * Hz];

    if (tid < Hz) yv[0][tid] = out[((size_t)b * Sz + t0) * Hz + tid];
    for (int idx = tid; idx < NCs * Hz; idx += 1024)
        VvL[idx] = Vv[(size_t)b * NCs * Hz + idx];
    __syncthreads();

    const float4* D0 = (const float4*)(Dm + (size_t)b * NCs * OO);
    const int off = i * 32 + q * 4;        // float4 index: row i, col q*16
    float4 cur[4], n1[4], n2[4];
#pragma unroll
    for (int v = 0; v < 4; ++v) cur[v] = D0[off + v];
    {
        int c1i = (NCs > 1) ? 1 : 0;
        const float4* Dn = D0 + (size_t)c1i * (OO / 4);
#pragma unroll
        for (int v = 0; v < 4; ++v) n1[v] = Dn[off + v];
    }

    for (int cs = 0; cs < NCs; ++cs) {
        int nc2 = (cs + 2 < NCs) ? cs + 2 : NCs - 1;
        const float4* Dn = D0 + (size_t)nc2 * (OO / 4);
#pragma unroll
        for (int v = 0; v < 4; ++v) n2[v] = Dn[off + v];   // stays in flight

        const int cb = cs & 1;
        const float* yp = &yv[cb][q * 16];
        float s = 0.f;
#pragma unroll
        for (int v = 0; v < 4; ++v)
            s += cur[v].x * yp[v * 4 + 0] + cur[v].y * yp[v * 4 + 1] +
                 cur[v].z * yp[v * 4 + 2] + cur[v].w * yp[v * 4 + 3];
        s += __shfl_xor(s, 1);
        s += __shfl_xor(s, 2);
        s += __shfl_xor(s, 4);

        if (q == 0) {
            float yn = yv[cb][i] + s + VvL[cs * Hz + i];
            yv[cb ^ 1][i] = yn;
            int t_end = t0 + (cs + 1) * CHUNK;
            if (t_end < Sz)
                out[((size_t)b * Sz + t_end) * Hz + i] = yn;  // boundary row
        }
        asm volatile("s_waitcnt lgkmcnt(0)" ::: "memory");
        __builtin_amdgcn_s_barrier();
        asm volatile("" ::: "memory");
#pragma unroll
        for (int v = 0; v < 4; ++v) { cur[v] = n1[v]; n1[v] = n2[v]; }
    }
}

// -------- stage c: 16-step replay per chunk (interior rows) --------
__global__ __launch_bounds__(1024) void k_chunk_c(
    const unsigned short* __restrict__ As, const float* __restrict__ Bs,
    float* __restrict__ out, int t0, int Lsteps, int NCs) {
    const int cs = blockIdx.x, b = blockIdx.y;
    const int tid = threadIdx.x;
    const int i = tid >> 3, p = tid & 7;
    const int t0c = t0 + cs * CHUNK;
    int Lc = Lsteps - cs * CHUNK; if (Lc > CHUNK) Lc = CHUNK;
    __shared__ __align__(16) float y[2][Hz];

    if (tid < Hz) y[0][tid] = out[((size_t)b * Sz + t0c) * Hz + tid];
    __syncthreads();

    const unsigned short* Abp =
        As + ((size_t)b * Lsteps + cs * CHUNK) * OO + i * Hz + p * 16;
    const float* Bsb = Bs + (size_t)b * NT * Hz;
    float* outb = out + (size_t)b * Sz * Hz;

    u16x8 c0 = *(const u16x8*)(Abp);
    u16x8 c1 = *(const u16x8*)(Abp + 8);
    int l1 = (Lc > 1) ? 1 : 0;
    u16x8 d0 = *(const u16x8*)(Abp + (size_t)l1 * OO);
    u16x8 d1 = *(const u16x8*)(Abp + (size_t)l1 * OO + 8);

    for (int lt = 0; lt < Lc; ++lt) {
        int ln = lt + 2; if (ln > Lc - 1) ln = Lc - 1;
        u16x8 e0 = *(const u16x8*)(Abp + (size_t)ln * OO);
        u16x8 e1 = *(const u16x8*)(Abp + (size_t)ln * OO + 8);

        const int cur = lt & 1;
        const float4* yp = (const float4*)&y[cur][p * 16];
        float4 y0v = yp[0], y1v = yp[1], y2v = yp[2], y3v = yp[3];

        float s;
        s  = bf2f(c0[0]) * y0v.x + bf2f(c0[1]) * y0v.y +
             bf2f(c0[2]) * y0v.z + bf2f(c0[3]) * y0v.w;
        s += bf2f(c0[4]) * y1v.x + bf2f(c0[5]) * y1v.y +
             bf2f(c0[6]) * y1v.z + bf2f(c0[7]) * y1v.w;
        s += bf2f(c1[0]) * y2v.x + bf2f(c1[1]) * y2v.y +
             bf2f(c1[2]) * y2v.z + bf2f(c1[3]) * y2v.w;
        s += bf2f(c1[4]) * y3v.x + bf2f(c1[5]) * y3v.y +
             bf2f(c1[6]) * y3v.z + bf2f(c1[7]) * y3v.w;
        s += __shfl_xor(s, 1);
        s += __shfl_xor(s, 2);
        s += __shfl_xor(s, 4);

        if (p == 0) {
            int t = t0c + lt;
            float st = s + Bsb[(size_t)t * Hz + i];
            float yn = y[cur][i] + st;
            y[cur ^ 1][i] = yn;
            if (((t + 1) & (CHUNK - 1)) != 0)        // boundaries: stage b
                outb[(size_t)(t + 1) * Hz + i] = yn;
        }
        c0 = d0; c1 = d1; d0 = e0; d1 = e1;
        // raw barrier: y[] is double-buffered, so only LDS (lgkm) must drain;
        // the e0/e1 global prefetch stays in flight across the barrier.
        asm volatile("s_waitcnt lgkmcnt(0)" ::: "memory");
        __builtin_amdgcn_s_barrier();
        asm volatile("" ::: "memory");
    }
}

// -------- fallback (ws tiny) --------
__global__ __launch_bounds__(1024) void k_fused(const float* __restrict__ X,
                                                const float* __restrict__ initW,
                                                const float* __restrict__ initb,
                                                const float* __restrict__ WA,
                                                const float* __restrict__ WB,
                                                float* __restrict__ out) {
    const int b = blockIdx.x, tid = threadIdx.x;
    const int i = tid >> 3, p = tid & 7;
    __shared__ float y[2][Hz];
    __shared__ float u[KK];

    if (tid < Hz) {
        float a = initb[tid];
        const float* xr = X + (size_t)b * Sz * Dz;
        const float* wr = initW + (size_t)tid * Dz;
        for (int d = 0; d < Dz; ++d) a += xr[d] * wr[d];
        y[0][tid] = a;
        out[(size_t)b * Sz * Hz + tid] = a;
    }
    __syncthreads();

    for (int t = 0; t < NT; ++t) {
        if (tid < KK)
            u[tid] = (tid == 0) ? DT
                                : X[((size_t)b * Sz + t + 1) * Dz + tid - 1] * DT;
        __syncthreads();
        const int cur = t & 1;
        float partial = 0.f;
        for (int jj = 0; jj < 16; ++jj) {
            int j = p * 16 + jj;
            const float* wr = WA + (size_t)(i * Hz + j) * KK;
            float a = 0.f;
            for (int d = 0; d < KK; ++d) a += wr[d] * u[d];
            partial += a * y[cur][j];
        }
        partial += __shfl_xor(partial, 1);
        partial += __shfl_xor(partial, 2);
        partial += __shfl_xor(partial, 4);
        if (p == 0) {
            const float* wb = WB + (size_t)i * KK;
            float bv = 0.f;
            for (int d = 0; d < KK; ++d) bv += wb[d] * u[d];
            float yn = y[cur][i] + partial + bv;
            y[cur ^ 1][i] = yn;
            out[(size_t)b * Sz * Hz + (size_t)(t + 1) * Hz + i] = yn;
        }
        __syncthreads();
    }
}

extern "C" void kernel_launch(void* const* d_in, const int* in_sizes, int n_in,
                              void* d_out, int out_size, void* d_ws,
                              size_t ws_size, hipStream_t stream) {
    const float* X = (const float*)d_in[0];
    const float* initW = (const float*)d_in[1];
    const float* initb = (const float*)d_in[2];
    const float* WA = (const float*)d_in[3];
    const float* WB = (const float*)d_in[4];
    float* out = (float*)d_out;

    // ws layout
    const size_t WH_OFF = 0;                          // 2 MB
    const size_t WL_OFF = 2097152;                    // 2 MB
    const size_t WA0_OFF = 4194304;                   // 64 KB
    const size_t XH_OFF = 4259840;                    // 512 KB (4096 x 64)
    const size_t XL_OFF = 4784128;                    // 512 KB
    const size_t BS_OFF = 5308416;                    // 2 MB (8*511*128 f32)
    const size_t base = 7401472;
    const size_t PER_SC = (size_t)Bz * OO * 4 +       // Dm per chunk-col
                          (size_t)Bz * Hz * 4 +       // Vv per chunk-col
                          (size_t)Bz * CHUNK * OO * 2;// As per chunk-col
    const int NC = (NT + CHUNK - 1) / CHUNK;          // 32

    long SC_max = (ws_size > base) ? (long)((ws_size - base) / PER_SC) : 0;
    if (SC_max >= 1) {
        if (SC_max > NC) SC_max = NC;
        int nS = (NC + (int)SC_max - 1) / (int)SC_max;
        int SC = (NC + nS - 1) / nS;

        unsigned short* Wh = (unsigned short*)((char*)d_ws + WH_OFF);
        unsigned short* Wl = (unsigned short*)((char*)d_ws + WL_OFF);
        float* WA0d = (float*)((char*)d_ws + WA0_OFF);
        unsigned short* Xh = (unsigned short*)((char*)d_ws + XH_OFF);
        unsigned short* Xl = (unsigned short*)((char*)d_ws + XL_OFF);
        float* Bs = (float*)((char*)d_ws + BS_OFF);
        float* Dm = (float*)((char*)d_ws + base);
        float* Vv = (float*)((char*)d_ws + base + (size_t)SC * Bz * OO * 4);
        unsigned short* As = (unsigned short*)((char*)d_ws + base +
                                               (size_t)SC * Bz * OO * 4 +
                                               (size_t)SC * Bz * Hz * 4);

        k_wsplit<<<512, 256, 0, stream>>>(WA, Wh, Wl, WA0d);
        k_y0<<<4, 256, 0, stream>>>(X, initW, initb, out);
        k_bs<<<2044, 256, 0, stream>>>(X, WB, Bs);

        for (int c0 = 0; c0 < NC; c0 += SC) {
            int t0 = c0 * CHUNK;
            int Lsteps = NT - t0;
            if (Lsteps > SC * CHUNK) Lsteps = SC * CHUNK;
            int NCs = (Lsteps + CHUNK - 1) / CHUNK;
            int M = Bz * Lsteps;
            int Mpad = (M + 127) & ~127;
            k_prep<<<128, 256, 0, stream>>>(X, Xh, Xl, t0, Lsteps);
            k_gemm_mfma<<<dim3(128, Mpad / 128), 256, 0, stream>>>(
                Xh, Xl, Wh, Wl, WA0d, As, M);
            k_chunk_a<<<dim3(NCs, Bz), 1024, 0, stream>>>(As, Bs, Dm, Vv, t0,
                                                          Lsteps, NCs);
            k_chunk_b<<<Bz, 1024, 0, stream>>>(Dm, Vv, out, t0, Lsteps, NCs);
            k_chunk_c<<<dim3(NCs, Bz), 1024, 0, stream>>>(As, Bs, out, t0,
                                                          Lsteps, NCs);
        }
    } else {
        k_fused<<<Bz, 1024, 0, stream>>>(X, initW, initb, WA, WB, out);
    }
}